// Round 11
// baseline (2229.774 us; speedup 1.0000x reference)
//
#include <hip/hip_runtime.h>
#include <hip/hip_bf16.h>
#include <cstdint>

#define B_   4
#define NTOK 6264
#define NPAD 6400
#define D_   512
#define NH   8
#define NLM  256
#define N0   6170
#define PADF (NPAD - NTOK)   // 136
#define MFC1 24704           // B_*N0 padded to x128
#define QE   ((long long)NPAD * 1536)

typedef __attribute__((ext_vector_type(8))) short short8_t;
typedef __attribute__((ext_vector_type(4))) float float4_t;

__device__ __forceinline__ ushort f2b(float x){
  __hip_bfloat16 h = __float2bfloat16(x); return *(ushort*)&h;
}
__device__ __forceinline__ float b2f(ushort u){
  __hip_bfloat16 h = *(__hip_bfloat16*)&u; return __bfloat162float(h);
}
__device__ __forceinline__ float gload(const void* p, int bf, long long i){
  return bf ? __bfloat162float(((const __hip_bfloat16*)p)[i]) : ((const float*)p)[i];
}
__device__ __forceinline__ void atomicMaxF(float* a, float v){
  atomicMax((int*)a, __float_as_int(v));
}
__device__ __forceinline__ void gl_lds16(const void* g, void* l){
  __builtin_amdgcn_global_load_lds(
      (const __attribute__((address_space(1))) void*)g,
      (__attribute__((address_space(3))) void*)l, 16, 0, 0);
}
// single-instruction 2^x (inputs here are tiny: |x| ~ 0.06, no range issues)
__device__ __forceinline__ float fexp2(float x){
#if __has_builtin(__builtin_amdgcn_exp2f)
  return __builtin_amdgcn_exp2f(x);
#else
  return __expf(x * 0.6931471805599453f);
#endif
}

// ===================== fast bf16 NT GEMM (m97-style) ======================
struct GB {
  const __hip_bfloat16* A; const __hip_bfloat16* Bm; void* C; const float* bias;
  int M, N, K, lda, ldb, ldc;
  long long aSO, aSI; int aIn;
  long long bSO, bSI; int bIn;
  long long cSO, cSI; int cIn;
  float beta; int cbf, relu, ksp, klen;
};

template<int BN>
__global__ __launch_bounds__(256) void gemm_bt(GB p){
  __shared__ __align__(16) __hip_bfloat16 As[128*64];
  __shared__ __align__(16) __hip_bfloat16 Bs[BN*64];
  int zz = blockIdx.z;
  int z = zz / p.ksp, ks = zz - z*p.ksp;
  int k0 = ks * p.klen;
  int kend = k0 + p.klen; if (kend > p.K) kend = p.K;
  const __hip_bfloat16* A  = p.A  + (long long)(z/p.aIn)*p.aSO + (long long)(z%p.aIn)*p.aSI;
  const __hip_bfloat16* Bm = p.Bm + (long long)(z/p.bIn)*p.bSO + (long long)(z%p.bIn)*p.bSI;
  long long cOff = (long long)(z/p.cIn)*p.cSO + (long long)(z%p.cIn)*p.cSI;
  int rowBase = blockIdx.y*128, colBase = blockIdx.x*BN;
  int t = threadIdx.x, lane = t & 63;
  int wv = __builtin_amdgcn_readfirstlane(t >> 6);
  int lm = lane & 15, lq = lane >> 4;
  int dr = lane >> 3, dc = lane & 7;
  constexpr int NF = (BN == 128) ? 4 : 2;
  int wm = (wv >> 1) * 64;
  int wn = (BN == 128) ? (wv & 1) * 64 : (wv & 1) * 32;
  float4_t acc[4][NF];
  #pragma unroll
  for (int mi = 0; mi < 4; mi++)
    #pragma unroll
    for (int nf = 0; nf < NF; nf++) acc[mi][nf] = (float4_t)0.f;

  for (int kb = k0; kb < kend; kb += 64){
    #pragma unroll
    for (int d = 0; d < 4; d++){
      int rg = wv*4 + d;
      int row = rg*8 + dr;
      int cc = dc ^ (row & 7);
      gl_lds16(A + (long long)(rowBase + row)*p.lda + kb + cc*8, &As[rg*8*64]);
    }
    #pragma unroll
    for (int d = 0; d < BN/32; d++){
      int rg = wv*(BN/32) + d;
      int row = rg*8 + dr;
      int cc = dc ^ (row & 7);
      gl_lds16(Bm + (long long)(colBase + row)*p.ldb + kb + cc*8, &Bs[rg*8*64]);
    }
    __syncthreads();
    short8_t af[2][4]; short8_t bfv[2][NF];
    #pragma unroll
    for (int ks2 = 0; ks2 < 2; ks2++){
      #pragma unroll
      for (int mi = 0; mi < 4; mi++){
        int r = wm + mi*16 + lm;
        int s = (ks2*4 + lq) ^ (r & 7);
        af[ks2][mi] = *(const short8_t*)&As[r*64 + s*8];
      }
      #pragma unroll
      for (int nf = 0; nf < NF; nf++){
        int r = wn + nf*16 + lm;
        int s = (ks2*4 + lq) ^ (r & 7);
        bfv[ks2][nf] = *(const short8_t*)&Bs[r*64 + s*8];
      }
    }
    #pragma unroll
    for (int ks2 = 0; ks2 < 2; ks2++)
      #pragma unroll
      for (int mi = 0; mi < 4; mi++)
        #pragma unroll
        for (int nf = 0; nf < NF; nf++)
          acc[mi][nf] = __builtin_amdgcn_mfma_f32_16x16x32_bf16(af[ks2][mi], bfv[ks2][nf], acc[mi][nf], 0, 0, 0);
    __syncthreads();
  }
  #pragma unroll
  for (int mi = 0; mi < 4; mi++){
    #pragma unroll
    for (int nf = 0; nf < NF; nf++){
      int c = colBase + wn + nf*16 + lm;
      #pragma unroll
      for (int r = 0; r < 4; r++){
        int m = rowBase + wm + mi*16 + lq*4 + r;
        if (m >= p.M) continue;
        float v = p.beta * acc[mi][nf][r];
        long long ci = cOff + (long long)m*p.ldc + c;
        if (p.ksp > 1){
          atomicAdd((float*)p.C + ci, v);
        } else {
          if (p.bias) v += p.bias[c];
          if (p.relu) v = fmaxf(v, 0.f);
          if (p.cbf) ((__hip_bfloat16*)p.C)[ci] = __float2bfloat16(v);
          else       ((float*)p.C)[ci] = v;
        }
      }
    }
  }
}

// ============== fast split (hi/lo) GEMM for pinv: 64x64 tiles, batch 32 ====
// Round-11: K=128 per stage (2 stage/compute rounds instead of 4) -> barrier
// count halves (8 -> 4). Buffers [64][128] bf16 = 16KB x4 = 64KB LDS; still
// 2 blocks/CU so occupancy unchanged. Store swizzle cc = dc16^(row&7) (low-3
// bit XOR over 16 chunks); read s = (ks2*4+lq)^(r&7) retrieves global chunk
// ks2*4+lq. K accumulation order identical (32-slices ascending) -> absmax
// unchanged. gemmS is launched 48x per run; this cuts its per-dispatch
// barrier-drain cost.
struct GS {
  const __hip_bfloat16* A; const __hip_bfloat16* B;
  __hip_bfloat16* outN; __hip_bfloat16* outT;
  long long PS;
  float scale, alphaT, sT;
};

__global__ __launch_bounds__(256) void gemm_bts(GS p){
  __shared__ __align__(16) __hip_bfloat16 Ah[64*128];
  __shared__ __align__(16) __hip_bfloat16 Al[64*128];
  __shared__ __align__(16) __hip_bfloat16 Bh[64*128];
  __shared__ __align__(16) __hip_bfloat16 Bl[64*128];
  int z = blockIdx.z;
  long long zo = (long long)z * 65536;
  const __hip_bfloat16* A = p.A + zo;
  const __hip_bfloat16* B = p.B + zo;
  int rowBase = blockIdx.y*64, colBase = blockIdx.x*64;
  int t = threadIdx.x, lane = t & 63;
  int wv = __builtin_amdgcn_readfirstlane(t >> 6);
  int lm = lane & 15, lq = lane >> 4;
  int dr4 = lane >> 4;          // 4 rows per DMA
  int dc16 = lane & 15;         // 16 chunks of 16B per 256B row
  int wm = (wv >> 1) * 32, wn = (wv & 1) * 32;
  float4_t acc[2][2];
  #pragma unroll
  for (int mi = 0; mi < 2; mi++){ acc[mi][0] = (float4_t)0.f; acc[mi][1] = (float4_t)0.f; }

  #pragma unroll 1
  for (int half = 0; half < 2; half++){
    int kb = half*128;
    #pragma unroll
    for (int d = 0; d < 4; d++){
      int rg = wv*4 + d;               // 16 row-groups of 4 rows
      int row = rg*4 + dr4;
      int cc = dc16 ^ (row & 7);
      gl_lds16(A +        (long long)(rowBase + row)*256 + kb + cc*8, &Ah[rg*4*128]);
      gl_lds16(A + p.PS + (long long)(rowBase + row)*256 + kb + cc*8, &Al[rg*4*128]);
      gl_lds16(B +        (long long)(colBase + row)*256 + kb + cc*8, &Bh[rg*4*128]);
      gl_lds16(B + p.PS + (long long)(colBase + row)*256 + kb + cc*8, &Bl[rg*4*128]);
    }
    __syncthreads();
    #pragma unroll
    for (int ks2 = 0; ks2 < 4; ks2++){
      short8_t ah[2], al2[2], bh[2], bl2[2];
      #pragma unroll
      for (int mi = 0; mi < 2; mi++){
        int r = wm + mi*16 + lm;
        int s = (ks2*4 + lq) ^ (r & 7);
        ah[mi]  = *(const short8_t*)&Ah[r*128 + s*8];
        al2[mi] = *(const short8_t*)&Al[r*128 + s*8];
      }
      #pragma unroll
      for (int nf = 0; nf < 2; nf++){
        int r = wn + nf*16 + lm;
        int s = (ks2*4 + lq) ^ (r & 7);
        bh[nf]  = *(const short8_t*)&Bh[r*128 + s*8];
        bl2[nf] = *(const short8_t*)&Bl[r*128 + s*8];
      }
      #pragma unroll
      for (int mi = 0; mi < 2; mi++)
        #pragma unroll
        for (int nf = 0; nf < 2; nf++){
          acc[mi][nf] = __builtin_amdgcn_mfma_f32_16x16x32_bf16(ah[mi],  bh[nf],  acc[mi][nf], 0, 0, 0);
          acc[mi][nf] = __builtin_amdgcn_mfma_f32_16x16x32_bf16(ah[mi],  bl2[nf], acc[mi][nf], 0, 0, 0);
          acc[mi][nf] = __builtin_amdgcn_mfma_f32_16x16x32_bf16(al2[mi], bh[nf],  acc[mi][nf], 0, 0, 0);
        }
    }
    __syncthreads();
  }
  #pragma unroll
  for (int mi = 0; mi < 2; mi++){
    #pragma unroll
    for (int nf = 0; nf < 2; nf++){
      int c = colBase + wn + nf*16 + lm;
      #pragma unroll
      for (int r = 0; r < 4; r++){
        int m = rowBase + wm + mi*16 + lq*4 + r;
        float v = p.scale * acc[mi][nf][r];
        if (p.outN){
          __hip_bfloat16 hi = __float2bfloat16(v);
          p.outN[zo + (long long)m*256 + c] = hi;
          p.outN[p.PS + zo + (long long)m*256 + c] = __float2bfloat16(v - __bfloat162float(hi));
        }
        if (p.outT){
          float w = p.alphaT * (m == c ? 1.f : 0.f) + p.sT * v;
          __hip_bfloat16 hi = __float2bfloat16(w);
          p.outT[zo + (long long)c*256 + m] = hi;
          p.outT[p.PS + zo + (long long)c*256 + m] = __float2bfloat16(w - __bfloat162float(hi));
        }
      }
    }
  }
}

// ====== fused sim3 (flash-style): S=QL@K^T, max-free softmax, O=P@V^T =====
__global__ __launch_bounds__(256) void sim3_fused(const __hip_bfloat16* QKV,
    const __hip_bfloat16* QL2, const __hip_bfloat16* VT, float* AVp, float* MLp){
  __shared__ __align__(16) __hip_bfloat16 Ks[64*64];
  __shared__ __align__(16) __hip_bfloat16 Ps[4*16*64];
  int z = blockIdx.y, b = z >> 3, h = z & 7;
  int r0 = blockIdx.x * 64;
  int ksp = blockIdx.z;
  int t = threadIdx.x, lane = t & 63;
  int wv = __builtin_amdgcn_readfirstlane(t >> 6);
  int lm = lane & 15, lq = lane >> 4;
  int dr = lane >> 3, dc = lane & 7;
  const __hip_bfloat16* Kb = QKV + (long long)b*QE + h*64 + 512;
  const __hip_bfloat16* Vb = VT + (long long)z*64*NPAD;

  // QL2 A-fragments (constant over key loop)
  short8_t aq[2];
  #pragma unroll
  for (int ks = 0; ks < 2; ks++)
    aq[ks] = *(const short8_t*)(QL2 + (long long)z*NLM*64 + (r0 + wv*16 + lm)*64 + ks*32 + lq*8);

  float l_run[4];
  float4_t oacc[4];
  #pragma unroll
  for (int r = 0; r < 4; r++) l_run[r] = 0.f;
  #pragma unroll
  for (int nf = 0; nf < 4; nf++) oacc[nf] = (float4_t)0.f;

  int kbase = ksp * (NPAD/4);
  for (int kt = 0; kt < (NPAD/4)/64; kt++){
    int k0 = kbase + kt*64;
    __syncthreads();
    // stage K-tile 64 keys x 64 d (swizzled), 2 DMA per wave
    #pragma unroll
    for (int d = 0; d < 2; d++){
      int rg = wv*2 + d;
      int row = rg*8 + dr;
      int cc = dc ^ (row & 7);
      gl_lds16(Kb + (long long)(k0 + row)*1536 + cc*8, &Ks[rg*8*64]);
    }
    __syncthreads();
    // S tile: 16 rows x 64 keys
    float4_t sacc[4];
    #pragma unroll
    for (int nf = 0; nf < 4; nf++) sacc[nf] = (float4_t)0.f;
    #pragma unroll
    for (int ks = 0; ks < 2; ks++){
      #pragma unroll
      for (int nf = 0; nf < 4; nf++){
        int r = nf*16 + lm;
        int s = (ks*4 + lq) ^ (r & 7);
        short8_t bb = *(const short8_t*)&Ks[r*64 + s*8];
        sacc[nf] = __builtin_amdgcn_mfma_f32_16x16x32_bf16(aq[ks], bb, sacc[nf], 0, 0, 0);
      }
    }
    // max-free exp; write unnormalized P' to per-wave Ps (same-wave, no barrier)
    #pragma unroll
    for (int reg = 0; reg < 4; reg++){
      int row = lq*4 + reg;
      #pragma unroll
      for (int nf = 0; nf < 4; nf++){
        float e = fexp2(sacc[nf][reg]);
        l_run[reg] += e;
        int col = nf*16 + lm;
        Ps[(wv*16 + row)*64 + (((col>>3) ^ (row&7))*8) + (col&7)] = __float2bfloat16(e);
      }
    }
    // PV: A = Ps rows (queries), B = VT rows (d), k = keys
    #pragma unroll
    for (int ks = 0; ks < 2; ks++){
      int s = (ks*4 + lq) ^ (lm & 7);
      short8_t ap = *(const short8_t*)&Ps[(wv*16 + lm)*64 + s*8];
      #pragma unroll
      for (int nf = 0; nf < 4; nf++){
        short8_t bb = *(const short8_t*)(Vb + (long long)(nf*16 + lm)*NPAD + k0 + ks*32 + lq*8);
        oacc[nf] = __builtin_amdgcn_mfma_f32_16x16x32_bf16(ap, bb, oacc[nf], 0, 0, 0);
      }
    }
  }
  // one-time row-sum reduce across the 16-lane (lm) group
  #pragma unroll
  for (int reg = 0; reg < 4; reg++)
    #pragma unroll
    for (int mm = 1; mm <= 8; mm <<= 1) l_run[reg] += __shfl_xor(l_run[reg], mm);
  // epilogue: unnormalized partials + l
  long long zb = (long long)(ksp*32 + z);
  #pragma unroll
  for (int nf = 0; nf < 4; nf++){
    #pragma unroll
    for (int reg = 0; reg < 4; reg++){
      int row = r0 + wv*16 + lq*4 + reg;
      AVp[zb*16384 + row*64 + nf*16 + lm] = oacc[nf][reg];
    }
  }
  if (lm == 0){
    #pragma unroll
    for (int reg = 0; reg < 4; reg++){
      int row = r0 + wv*16 + lq*4 + reg;
      MLp[zb*256 + row] = l_run[reg];
    }
  }
}

// merge 4 key-split partials -> AV [z][256][64] f32 (plain sums, m=0)
__global__ __launch_bounds__(256) void av_merge(const float* AVp, const float* MLp, float* AV){
  int i = blockIdx.x*256 + threadIdx.x;
  int d = i & 63, row = (i >> 6) & 255, z = i >> 14;
  float osum = 0.f, lsum = 0.f;
  #pragma unroll
  for (int s = 0; s < 4; s++){
    lsum += MLp[(long long)(s*32+z)*256 + row];
    osum += AVp[(long long)(s*32+z)*16384 + row*64 + d];
  }
  AV[(long long)z*16384 + row*64 + d] = osum / lsum;
}

// ============ fused sim1: S=Q@KL2^T (scale folded), exp2, O=P@ZV ==========
// DMA staging (round-6, verified): K tile staged to LDS via global_load_lds
// (compiler cannot sink DMA); same 32KB buffer reused for ZVT sub-tiles.
__global__ __launch_bounds__(256) void sim1_fused(const __hip_bfloat16* QKV,
    const __hip_bfloat16* KL2, const __hip_bfloat16* ZVT, float* OUT1){
  __shared__ __align__(16) __hip_bfloat16 Ps[64*256];
  __shared__ __align__(16) __hip_bfloat16 Sb[256*64];
  int z = blockIdx.y, b = z >> 3, h = z & 7;
  int n0 = blockIdx.x * 64;
  int t = threadIdx.x, lane = t & 63;
  int wv = __builtin_amdgcn_readfirstlane(t >> 6);
  int lm = lane & 15, lq = lane >> 4;
  int dr = lane >> 3, dc = lane & 7;
  const __hip_bfloat16* Qb = QKV + (long long)b*QE + h*64;
  const __hip_bfloat16* Kb = KL2 + (long long)z*NLM*64;
  const __hip_bfloat16* Zb = ZVT + (long long)z*64*256;

  // stage K tile [256 landmarks][64 d] -> Sb (swizzled), 8 DMA per wave
  #pragma unroll
  for (int d = 0; d < 8; d++){
    int rg = wv*8 + d;
    int row = rg*8 + dr;           // row & 7 == dr
    gl_lds16(Kb + (long long)row*64 + (dc ^ dr)*8, &Sb[rg*8*64]);
  }
  int qrow = n0 + wv*16 + lm;
  short8_t aq[2];
  aq[0] = *(const short8_t*)(Qb + (long long)qrow*1536 + lq*8);
  aq[1] = *(const short8_t*)(Qb + (long long)qrow*1536 + 32 + lq*8);
  __syncthreads();                  // drains DMA + Q loads

  float psum[4] = {0.f, 0.f, 0.f, 0.f};
  int rowb = wv*16 + lq*4;
  #pragma unroll
  for (int nf = 0; nf < 16; nf++){
    float4_t s = (float4_t)0.f;
    #pragma unroll
    for (int ks = 0; ks < 2; ks++){
      int r = nf*16 + lm;
      int s2 = (ks*4 + lq) ^ (r & 7);
      short8_t bb = *(const short8_t*)&Sb[r*64 + s2*8];
      s = __builtin_amdgcn_mfma_f32_16x16x32_bf16(aq[ks], bb, s, 0, 0, 0);
    }
    int col = nf*16 + lm;
    #pragma unroll
    for (int reg = 0; reg < 4; reg++){
      float e = fexp2(s[reg]);
      psum[reg] += e;
      int row = rowb + reg;
      Ps[row*256 + (((col>>3) ^ (row&7))*8) + (col & 7)] = __float2bfloat16(e);
    }
  }
  __syncthreads();                  // all waves done reading K from Sb
  // stage Z tile [64 d][256 keys] as 4 sub-tiles [64][64] into Sb (swizzled)
  #pragma unroll
  for (int d = 0; d < 8; d++){
    int rg = wv*8 + d;
    int sb = rg >> 3, rgl = rg & 7;
    int row = rgl*8 + dr;          // row & 7 == dr
    gl_lds16(Zb + (long long)row*256 + sb*64 + (dc ^ dr)*8,
             &Sb[sb*4096 + rgl*8*64]);
  }
  __syncthreads();                  // drains Z DMA

  float4_t oacc[4];
  #pragma unroll
  for (int nf = 0; nf < 4; nf++) oacc[nf] = (float4_t)0.f;
  int prow = wv*16 + lm;
  #pragma unroll
  for (int ks = 0; ks < 8; ks++){
    int chunk = (ks*4 + lq) ^ (lm & 7);
    short8_t a = *(const short8_t*)&Ps[prow*256 + chunk*8];
    int lc = (ks & 1)*4 + lq;
    #pragma unroll
    for (int nf = 0; nf < 4; nf++){
      int r = nf*16 + lm;
      short8_t bb = *(const short8_t*)&Sb[(ks>>1)*4096 + r*64 + (lc ^ (r & 7))*8];
      oacc[nf] = __builtin_amdgcn_mfma_f32_16x16x32_bf16(a, bb, oacc[nf], 0, 0, 0);
    }
  }
  // deferred row-sum reduce + normalization
  #pragma unroll
  for (int reg = 0; reg < 4; reg++){
    #pragma unroll
    for (int m = 1; m <= 8; m <<= 1) psum[reg] += __shfl_xor(psum[reg], m);
    psum[reg] = 1.f / psum[reg];
  }
  #pragma unroll
  for (int nf = 0; nf < 4; nf++){
    #pragma unroll
    for (int reg = 0; reg < 4; reg++){
      int tok = n0 + wv*16 + lq*4 + reg;
      OUT1[((long long)b*NPAD + tok)*D_ + h*64 + nf*16 + lm] = oacc[nf][reg] * psum[reg];
    }
  }
}

// ============================= softmax ====================================
__global__ __launch_bounds__(256) void softmax256_split(float* S, __hip_bfloat16* P, long long PS){
  long long row = blockIdx.x;
  float* p = S + row * 256;
  int t = threadIdx.x;
  float v = p[t];
  __shared__ float red[256];
  red[t] = v; __syncthreads();
  for (int s = 128; s; s >>= 1){ if (t < s) red[t] = fmaxf(red[t], red[t+s]); __syncthreads(); }
  float m = red[0]; __syncthreads();
  float e = __expf(v - m);
  red[t] = e; __syncthreads();
  for (int s = 128; s; s >>= 1){ if (t < s) red[t] += red[t+s]; __syncthreads(); }
  float r = e / red[0];
  p[t] = r;
  __hip_bfloat16 hi = __float2bfloat16(r);
  P[row*256 + t] = hi;
  P[PS + row*256 + t] = __float2bfloat16(r - __bfloat162float(hi));
}

// ============================ LN / misc ===================================
__global__ __launch_bounds__(256) void ln_pad(const float* H, __hip_bfloat16* X,
                                              const float* g, const float* bb){
  int p = blockIdx.x, b = blockIdx.y, t = threadIdx.x;
  __hip_bfloat16* xo = X + ((long long)b * NPAD + p) * D_;
  if (p < PADF){ xo[t] = __float2bfloat16(0.f); xo[t + 256] = __float2bfloat16(0.f); return; }
  const float* hi = H + ((long long)b * NTOK + (p - PADF)) * D_;
  float x0 = hi[t], x1 = hi[t + 256];
  __shared__ float r1[256], r2[256];
  r1[t] = x0 + x1; r2[t] = x0*x0 + x1*x1;
  __syncthreads();
  for (int s = 128; s; s >>= 1){ if (t < s){ r1[t] += r1[t+s]; r2[t] += r2[t+s]; } __syncthreads(); }
  float mu = r1[0] * (1.f / D_);
  float var = r2[0] * (1.f / D_) - mu*mu;
  float rs = rsqrtf(var + 1e-5f);
  xo[t]       = __float2bfloat16((x0 - mu) * rs * g[t]       + bb[t]);
  xo[t + 256] = __float2bfloat16((x1 - mu) * rs * g[t + 256] + bb[t + 256]);
}

__global__ __launch_bounds__(256) void final_ln(const float* H, const float* g,
                                                const float* bb, float* out){
  int b = blockIdx.x, t = threadIdx.x;
  const float* hi = H + (long long)b * NTOK * D_;
  float x0 = hi[t], x1 = hi[t + 256];
  __shared__ float r1[256], r2[256];
  r1[t] = x0 + x1; r2[t] = x0*x0 + x1*x1;
  __syncthreads();
  for (int s = 128; s; s >>= 1){ if (t < s){ r1[t] += r1[t+s]; r2[t] += r2[t+s]; } __syncthreads(); }
  float mu = r1[0] * (1.f / D_);
  float var = r2[0] * (1.f / D_) - mu*mu;
  float rs = rsqrtf(var + 1e-5f);
  out[b*D_ + t]       = (x0 - mu) * rs * g[t]       + bb[t];
  out[b*D_ + t + 256] = (x1 - mu) * rs * g[t + 256] + bb[t + 256];
}

__global__ __launch_bounds__(256) void build_h(const float* h0, const float* cls, float* H){
  int tpos = blockIdx.x, b = blockIdx.y, t = threadIdx.x;
  float* dst = H + ((long long)b * NTOK + tpos) * D_;
  if (tpos == 0){ dst[t] = cls[t]; dst[t + 256] = cls[t + 256]; return; }
  int i = tpos - 1, src;
  if (i < 10)        src = i;
  else if (i < 179){ int j = i - 10;  src = 10  + (j < 160  ? j : j - 160);  }
  else             { int j = i - 179; src = 170 + (j < 6000 ? j : j - 6000); }
  const float* s = h0 + ((long long)b * N0 + src) * D_;
  dst[t] = s[t]; dst[t + 256] = s[t + 256];
}

__global__ __launch_bounds__(256) void cvt_pad_x(const float* x, __hip_bfloat16* Xb){
  int row = blockIdx.x, t = threadIdx.x;
  __hip_bfloat16* o = Xb + (long long)row * 768;
  if (row >= B_*N0){ o[t] = __float2bfloat16(0.f); o[t+256] = __float2bfloat16(0.f); o[t+512] = __float2bfloat16(0.f); return; }
  const float* s = x + (long long)row * 768;
  o[t]     = __float2bfloat16(s[t]);
  o[t+256] = __float2bfloat16(s[t+256]);
  o[t+512] = __float2bfloat16(s[t+512]);
}

__global__ __launch_bounds__(256) void tr_cvt(const void* in, int inbf, int ldin,
    long long iSO, long long iSI, int iIn, __hip_bfloat16* outp, long long oSO,
    int R, int C){
  __shared__ float sm[32][33];
  int z = blockIdx.z;
  long long ib = (long long)(z/iIn)*iSO + (long long)(z%iIn)*iSI;
  int r0 = blockIdx.y*32, c0 = blockIdx.x*32;
  int tx = threadIdx.x & 31, ty = threadIdx.x >> 5;
  for (int rr = ty; rr < 32; rr += 8)
    sm[rr][tx] = gload(in, inbf, ib + (long long)(r0+rr)*ldin + c0 + tx);
  __syncthreads();
  for (int cc = ty; cc < 32; cc += 8)
    outp[z*oSO + (long long)(c0+cc)*R + r0 + tx] = __float2bfloat16(sm[tx][cc]);
}

// QL/KL: original scales (feed a2 GEMM). QL2/KL2: x log2(e) (feed exp2 paths).
__global__ __launch_bounds__(256) void landmarks2(const __hip_bfloat16* QKV,
                                                  __hip_bfloat16* QL, __hip_bfloat16* KL,
                                                  __hip_bfloat16* QL2, __hip_bfloat16* KL2){
  int j = blockIdx.x, b = blockIdx.y, t = threadIdx.x;
  const __hip_bfloat16* base = QKV + ((long long)b * NPAD + j*25) * 1536;
  float q0 = 0.f, q1 = 0.f, k0 = 0.f, k1 = 0.f;
  #pragma unroll 5
  for (int i = 0; i < 25; i++){
    const __hip_bfloat16* row = base + (long long)i*1536;
    q0 += __bfloat162float(row[t]);
    q1 += __bfloat162float(row[t + 256]);
    k0 += __bfloat162float(row[512 + t]);
    k1 += __bfloat162float(row[512 + t + 256]);
  }
  int h0 = t >> 6, d0 = t & 63;
  int h1 = (t + 256) >> 6, d1 = (t + 256) & 63;
  const float C2 = 0.007213475204444817f;  // 0.04 * 0.125 * log2(e)
  long long i0 = ((long long)(b*8 + h0) * NLM + j) * 64 + d0;
  long long i1 = ((long long)(b*8 + h1) * NLM + j) * 64 + d1;
  QL[i0] = __float2bfloat16(q0 * 0.005f);
  QL[i1] = __float2bfloat16(q1 * 0.005f);
  KL[i0] = __float2bfloat16(k0 * 0.04f);
  KL[i1] = __float2bfloat16(k1 * 0.04f);
  QL2[i0] = __float2bfloat16(q0 * C2);
  QL2[i1] = __float2bfloat16(q1 * C2);
  KL2[i0] = __float2bfloat16(k0 * C2);
  KL2[i1] = __float2bfloat16(k1 * C2);
}

__global__ void init_sc(float* sc){ sc[0] = 0.f; sc[1] = 0.f; }

__global__ __launch_bounds__(256) void colsum_max(const float* A2, float* sc){
  int z = blockIdx.x, t = threadIdx.x;
  const float* a = A2 + (long long)z * 65536;
  float s = 0.f;
  for (int i = 0; i < 256; i++) s += fabsf(a[i*256 + t]);
  __shared__ float red[256];
  red[t] = s; __syncthreads();
  for (int st = 128; st; st >>= 1){ if (t < st) red[t] = fmaxf(red[t], red[t+st]); __syncthreads(); }
  if (t == 0) atomicMaxF(sc + 0, red[0]);
}

__global__ __launch_bounds__(256) void rowsum_max(const float* A2, float* sc){
  int z = blockIdx.x, t = threadIdx.x, w = t >> 6, l = t & 63;
  const float* a = A2 + (long long)z * 65536;
  float mx = 0.f;
  for (int i = w*64; i < (w+1)*64; i++){
    float s = fabsf(a[i*256 + l]) + fabsf(a[i*256 + l + 64])
            + fabsf(a[i*256 + l + 128]) + fabsf(a[i*256 + l + 192]);
    for (int m = 32; m; m >>= 1) s += __shfl_xor(s, m);
    mx = fmaxf(mx, s);
  }
  __shared__ float red[4];
  if (l == 0) red[w] = mx;
  __syncthreads();
  if (t == 0) atomicMaxF(sc + 1, fmaxf(fmaxf(red[0], red[1]), fmaxf(red[2], red[3])));
}

__global__ __launch_bounds__(256) void zinit_split(const float* A2,
    __hip_bfloat16* ZN, __hip_bfloat16* ZT, long long PS, const float* sc){
  int j = blockIdx.x, z = blockIdx.y, i = threadIdx.x;
  float inv = 1.f / (sc[0] * sc[1]);
  float v = A2[(long long)z*65536 + i*256 + j] * inv;
  __hip_bfloat16 hi = __float2bfloat16(v);
  __hip_bfloat16 lo = __float2bfloat16(v - __bfloat162float(hi));
  long long zo = (long long)z*65536;
  ZN[zo + j*256 + i] = hi; ZN[PS + zo + j*256 + i] = lo;
  ZT[zo + i*256 + j] = hi; ZT[PS + zo + i*256 + j] = lo;
}

// LDS-staged depthwise conv (round-10, verified): stage 48 V rows once,
// 4 sequential n-steps per thread from LDS. 11x less cache traffic.
__global__ __launch_bounds__(256) void dwconv_cvt2(const __hip_bfloat16* QKV, const float* rw,
                                                   const float* OUT1, __hip_bfloat16* OUT1b){
  __shared__ __align__(16) __hip_bfloat16 Sv[48*512];   // 48 KB
  int t = threadIdx.x, lane = t & 63;
  int wv = __builtin_amdgcn_readfirstlane(t >> 6);
  int n0 = blockIdx.x * 16;
  int b = blockIdx.y;
  const __hip_bfloat16* Vb = QKV + (long long)b * NPAD * 1536 + 1024;
  // stage rows n0-16 .. n0+31 (one wave stages one 1KB row per DMA)
  for (int r = wv; r < 48; r += 4){
    int nn = n0 - 16 + r;
    if (nn >= 0 && nn < NPAD){
      gl_lds16(Vb + (long long)nn*1536 + lane*8, &Sv[r*512]);
    } else {
      short8_t zz = {0,0,0,0,0,0,0,0};
      *(short8_t*)&Sv[r*512 + lane*8] = zz;
    }
  }
  int ch0 = lane * 8;
  int h = lane >> 3;
  float w[33];
  #pragma unroll
  for (int k = 0; k < 33; k++) w[k] = rw[h*33 + k];
  __syncthreads();
  #pragma unroll 1
  for (int step = 0; step < 4; step++){
    int nl = wv + step*4;            // local token 0..15
    int n = n0 + nl;
    float acc[8] = {};
    #pragma unroll
    for (int k = 0; k < 33; k++){
      short8_t v8 = *(const short8_t*)&Sv[(nl + k)*512 + ch0];
      #pragma unroll
      for (int j = 0; j < 8; j++) acc[j] += w[k] * b2f((ushort)v8[j]);
    }
    long long idx = ((long long)b * NPAD + n) * D_ + ch0;
    float4 o0 = *(const float4*)(OUT1 + idx);
    float4 o1 = *(const float4*)(OUT1 + idx + 4);
    short8_t o;
    o[0] = (short)f2b(o0.x + acc[0]); o[1] = (short)f2b(o0.y + acc[1]);
    o[2] = (short)f2b(o0.z + acc[2]); o[3] = (short)f2b(o0.w + acc[3]);
    o[4] = (short)f2b(o1.x + acc[4]); o[5] = (short)f2b(o1.y + acc[5]);
    o[6] = (short)f2b(o1.z + acc[6]); o[7] = (short)f2b(o1.w + acc[7]);
    *(short8_t*)((ushort*)OUT1b + idx) = o;
  }
}

__global__ __launch_bounds__(512) void resid_add(float* H, const float* O2, const float* ob){
  int i = blockIdx.x, b = blockIdx.y, t = threadIdx.x;
  H[((long long)b * NTOK + i) * D_ + t] +=
      O2[((long long)b * NPAD + i + PADF) * D_ + t] + ob[t];
}

// ------------------- PPEG: LDS weights + float4 staging -------------------
__global__ __launch_bounds__(256) void transpose_w(const float* w, float* wt, int KK){
  int i = blockIdx.x*256 + threadIdx.x;
  if (i < 512*KK){ int ch = i / KK, k = i - ch*KK; wt[(long long)k*512 + ch] = w[i]; }
}

// 16x16 spatial tile x 32 ch, 512 threads (thread = 1 ch, 1 y-row).
// Two sequential 8-wide halves (#pragma unroll 1): live state acc[8]+v[14],
// 96 VGPR, no spill (proven 82us). pk_fma attempted twice (r7/r8); both
// spilled at an observed 128-VGPR cap -> keep scalar form.
__global__ __launch_bounds__(512, 2) void ppeg_tiled(const float* H, float* P,
    const float* t7, const float* t5, const float* t3,
    const float* b7, const float* b5, const float* b3,
    int base, int W, int tilesX){
  __shared__ float smem[484*32];   // 22x22 patch x 32 ch = 61.9 KB
  __shared__ float wsm[83*32 + 32];// 10.6 KB weights + bias-sum
  int ty0 = (blockIdx.x / tilesX) * 16, tx0 = (blockIdx.x % tilesX) * 16;
  int c0 = blockIdx.y * 32, b = blockIdx.z;
  int t = threadIdx.x, ch = t & 31, y = t >> 5;
  int cc = c0 + ch;
  // cooperative weight load (per block)
  for (int i = t; i < 83*32; i += 512){
    int k = i >> 5, c = c0 + (i & 31);
    float w;
    if (k < 49)      w = t7[k*512 + c];
    else if (k < 74) w = t5[(k-49)*512 + c];
    else             w = t3[(k-74)*512 + c];
    wsm[i] = w;
  }
  if (t < 32) wsm[83*32 + t] = b7[c0+t] + b5[c0+t] + b3[c0+t];
  // patch staging (float4 per thread-iter): 484 pos x 8 float4 = 3872 loads
  {
    const float* Hb = H + ((long long)b * NTOK + base) * D_ + c0;
    for (int q = t; q < 3872; q += 512){
      int pos = q >> 3, c4 = (q & 7) * 4;
      int py = pos / 22, px = pos - py*22;
      int yy = ty0 + py - 3, xx = tx0 + px - 3;
      float4 v = make_float4(0.f, 0.f, 0.f, 0.f);
      if (yy >= 0 && yy < W && xx >= 0 && xx < W)
        v = *(const float4*)(Hb + (long long)(yy*W + xx)*D_ + c4);
      *(float4*)&smem[pos*32 + c4] = v;
    }
  }
  __syncthreads();
  int gy = ty0 + y;
  float bsum = wsm[83*32 + ch];
  #pragma unroll 1
  for (int xh = 0; xh < 2; xh++){
    int xb = xh * 8;
    float acc[8];
    #pragma unroll
    for (int x = 0; x < 8; x++) acc[x] = bsum;
    #pragma unroll
    for (int r = 0; r < 7; r++){
      float v[14];
      #pragma unroll
      for (int xx = 0; xx < 14; xx++) v[xx] = smem[((y + r)*22 + xb + xx)*32 + ch];
      #pragma unroll
      for (int kx = 0; kx < 7; kx++){
        float w = wsm[(r*7 + kx)*32 + ch];
        #pragma unroll
        for (int x = 0; x < 8; x++) acc[x] += w * v[x + kx];
      }
      if (r >= 1 && r <= 5){
        #pragma unroll
        for (int kx = 0; kx < 5; kx++){
          float w = wsm[(49 + (r-1)*5 + kx)*32 + ch];
          #pragma unroll
          for (int x = 0; x < 8; x++) acc[x] += w * v[x + kx + 1];
        }
      }
      if (r >= 2 && r <= 4){
        #pragma unroll
        for (int kx = 0; kx < 3; kx++){
          float w = wsm[(74 + (r-2)*3 + kx)*32 + ch];
          #pragma unroll
          for (int x = 0; x < 8; x++) acc[x] += w * v[x + kx + 2];
        }
      }
      if (r == 3){
        #pragma unroll
        for (int x = 0; x < 8; x++) acc[x] += v[x + 3];
      }
    }
    if (gy < W){
      #pragma unroll
      for (int x = 0; x < 8; x++){
        int gx = tx0 + xb + x;
        if (gx < W)
          P[((long long)b * W * W + gy*W + gx) * D_ + cc] = acc[x];
      }
    }
  }
}

__global__ __launch_bounds__(512) void ppeg_copy(float* H, const float* P, int base, int W){
  int pos = blockIdx.x, b = blockIdx.y, t = threadIdx.x;
  H[((long long)b * NTOK + base + pos) * D_ + t] = P[((long long)b * W * W + pos) * D_ + t];
}

// ============================== host side =================================
static void gemmB(hipStream_t st, int BN,
                  const __hip_bfloat16* A, int lda, long long aSO, long long aSI, int aIn,
                  const __hip_bfloat16* Bm, int ldb, long long bSO, long long bSI, int bIn,
                  void* C, int ldc, long long cSO, long long cSI, int cIn, int cbf,
                  int M, int N, int K, int batch,
                  const float* bias, float beta, int relu, int ksp = 1, int klen = 0){
  GB p;
  p.A = A; p.Bm = Bm; p.C = C; p.bias = bias;
  p.M = M; p.N = N; p.K = K; p.lda = lda; p.ldb = ldb; p.ldc = ldc;
  p.aSO = aSO; p.aSI = aSI; p.aIn = aIn;
  p.bSO = bSO; p.bSI = bSI; p.bIn = bIn;
  p.cSO = cSO; p.cSI = cSI; p.cIn = cIn; p.cbf = cbf;
  p.beta = beta; p.relu = relu; p.ksp = ksp; p.klen = (klen > 0) ? klen : K;
  dim3 g(N/BN, (M + 127)/128, batch * ksp), b(256);
  if (BN == 128) gemm_bt<128><<<g, b, 0, st>>>(p);
  else           gemm_bt<64><<<g, b, 0, st>>>(p);
}

static void gemmS(hipStream_t st, const ushort* A, const ushort* B,
                  ushort* oN, ushort* oT, float scale, float alphaT, float sT){
  GS p;
  p.A = (const __hip_bfloat16*)A; p.B = (const __hip_bfloat16*)B;
  p.outN = (__hip_bfloat16*)oN; p.outT = (__hip_bfloat16*)oT;
  p.PS = 2097152; p.scale = scale; p.alphaT = alphaT; p.sT = sT;
  dim3 g(4, 4, 32), b(256);
  gemm_bts<<<g, b, 0, st>>>(p);
}

extern "C" void kernel_launch(void* const* d_in, const int* in_sizes, int n_in,
                              void* d_out, int out_size, void* d_ws, size_t ws_size,
                              hipStream_t stream){
  const float* x      = (const float*)d_in[0];
  const float* fc1_w  = (const float*)d_in[1];
  const float* fc1_b  = (const float*)d_in[2];
  const float* cls    = (const float*)d_in[3];
  const float* l1_ng  = (const float*)d_in[4];
  const float* l1_nb  = (const float*)d_in[5];
  const float* l1_qkv = (const float*)d_in[6];
  const float* l1_ow  = (const float*)d_in[7];
  const float* l1_ob  = (const float*)d_in[8];
  const float* l1_rw  = (const float*)d_in[9];
  const float* ct_w7  = (const float*)d_in[10];
  const float* ct_b7  = (const float*)d_in[11];
  const float* ct_w5  = (const float*)d_in[12];
  const float* ct_b5  = (const float*)d_in[13];
  const float* ct_w3  = (const float*)d_in[14];
  const float* ct_b3  = (const float*)d_in[15];
  const float* pt_w7  = (const float*)d_in[16];
  const float* pt_b7  = (const float*)d_in[17];
  const float* pt_w5  = (const float*)d_in[18];
  const float* pt_b5  = (const float*)d_in[19];
  const float* pt_w3  = (const float*)d_in[20];
  const float* pt_b3  = (const float*)d_in[21];
  const float* l2_ng  = (const float*)d_in[22];
  const float* l2_nb  = (const float*)d_in[23];
  const float* l2_qkv = (const float*)d_in[24];
  const float* l2_ow  = (const float*)d_in[25];
  const float* l2_ob  = (const float*)d_in[26];
  const float* l2_rw  = (const float*)d_in[27];
  const float* nrm_g  = (const float*)d_in[28];
  const float* nrm_b  = (const float*)d_in[29];
  float* out = (float*)d_out;

  // ---- workspace layout (float units); SIMC last ----
  float* ws    = (float*)d_ws;
  float* H     = ws;                      // 12,828,672
  float* BUF   = H + 12828672;            // 13,107,200
  float* QKVr  = BUF + 13107200;          // 19,660,800
  float* QLf   = QKVr + 19660800;         //    262,144
  float* KLf   = QLf + 262144;            //    262,144
  float* AV    = KLf + 262144;            //    524,288
  float* AVTf  = AV + 524288;             //    262,144
  float* ZVf   = AVTf + 262144;           //    262,144
  float* ZVTf  = ZVf + 262144;            //    262,144
  float* WQf   = ZVTf + 262144;           //    393,216
  float* WFf   = WQf + 393216;            //    196,608
  float* WOf   = WFf + 196608;            //    131,072
  float* PWT   = WOf + 131072;            //     84,992
  float* SC    = PWT + 84992;             //          8
  float* SIMC  = SC + 8;                  //  rest (pinv planes / AVp / OUT1b)
  float* tc7 = PWT, *tc5 = tc7 + 49*512, *tc3 = tc5 + 25*512;
  float* tp7 = tc3 + 9*512, *tp5 = tp7 + 49*512, *tp3 = tp5 + 25*512;

  // pinv scratch: A2 f32 + hi/lo plane pairs (PS = 2,097,152 bf16 elems)
  float*  A2   = BUF;
  ushort* a2P  = (ushort*)(BUF + 2097152);
  ushort* zn_N = (ushort*)(BUF + 4194304);
  ushort* zn_T = (ushort*)(BUF + 6291456);
  ushort* zc_N = (ushort*)(BUF + 8388608);
  ushort* zc_T = (ushort*)(BUF + 10485760);
  ushort* azP  = (ushort*)SIMC;
  ushort* w1T  = (ushort*)SIMC + 4194304;
  ushort* w2T  = (ushort*)SIMC + 8388608;
  float*  AVp  = SIMC;                    // 2,097,152 f32 (post-pinv)
  float*  MLp  = SIMC + 2097152;          //    32,768 f32 (l only)

  __hip_bfloat16* Xb    = (__hip_bfloat16*)QKVr;
  __hip_bfloat16* QKV   = (__hip_bfloat16*)QKVr;
  float*          PROJ  = QKVr;
  __hip_bfloat16* XLNb  = (__hip_bfloat16*)BUF;
  __hip_bfloat16* VT    = (__hip_bfloat16*)BUF;         // [32][64][6400]
  __hip_bfloat16* OUT1b = (__hip_bfloat16*)SIMC;
  __hip_bfloat16* QLb   = (__hip_bfloat16*)QLf;
  __hip_bfloat16* KLb   = (__hip_bfloat16*)KLf;
  // exp2-prescaled copies, in dead windows:
  __hip_bfloat16* QL2b  = (__hip_bfloat16*)AV;
  __hip_bfloat16* KL2b  = (__hip_bfloat16*)WQf;
  __hip_bfloat16* AVT   = (__hip_bfloat16*)AVTf;
  __hip_bfloat16* Zvb   = (__hip_bfloat16*)ZVf;
  __hip_bfloat16* ZVT   = (__hip_bfloat16*)ZVTf;
  __hip_bfloat16* WqkvT = (__hip_bfloat16*)WQf;
  __hip_bfloat16* Wfc1T = (__hip_bfloat16*)WFf;
  __hip_bfloat16* WoutT = (__hip_bfloat16*)WOf;

  // ---- one-time weight prep
  transpose_w<<<(512*49+255)/256, 256, 0, stream>>>(ct_w7, tc7, 49);
  transpose_w<<<(512*25+255)/256, 256, 0, stream>>>(ct_w5, tc5, 25);
  transpose_w<<<(512* 9+255)/256, 256, 0, stream>>>(ct_w3, tc3,  9);
  transpose_w<<<(512*49+255)/256, 256, 0, stream>>>(pt_w7, tp7, 49);
  transpose_w<<<(512*25+255)/256, 256, 0, stream>>>(pt_w5, tp5, 25);
  transpose_w<<<(512* 9+255)/256, 256, 0, stream>>>(pt_w3, tp3,  9);
  tr_cvt<<<dim3(512/32, 768/32, 1), 256, 0, stream>>>(fc1_w, 0, 512, 0,0,1, Wfc1T, 0, 768, 512);

  // ---- fc1 + relu -> h0 (BUF f32); gather into H
  cvt_pad_x<<<MFC1, 256, 0, stream>>>(x, Xb);
  gemmB(stream, 128, Xb, 768, 0,0,1, Wfc1T, 768, 0,0,1, BUF, 512, 0,0,1,0,
        MFC1, 512, 768, 1, fc1_b, 1.f, 1);
  build_h<<<dim3(NTOK, B_), 256, 0, stream>>>(BUF, cls, H);

  auto attn_layer = [&](const float* ng, const float* nb, const float* qkvw,
                        const float* outw, const float* outb, const float* resw){
    tr_cvt<<<dim3(1536/32, 512/32, 1), 256, 0, stream>>>(qkvw, 0, 1536, 0,0,1, WqkvT, 0, 512, 1536);
    tr_cvt<<<dim3(512/32, 512/32, 1), 256, 0, stream>>>(outw, 0, 512, 0,0,1, WoutT, 0, 512, 512);
    ln_pad<<<dim3(NPAD, B_), 256, 0, stream>>>(H, XLNb, ng, nb);
    gemmB(stream, 128, XLNb, 512, 0,0,1, WqkvT, 512, 0,0,1, QKV, 1536, 0,0,1,1,
          B_*NPAD, 1536, 512, 1, nullptr, 1.f, 0);
    landmarks2<<<dim3(NLM, B_), 256, 0, stream>>>(QKV, QLb, KLb, QL2b, KL2b);
    // a2 = softmax(q_l @ k_l^T): f32 + hi/lo planes
    gemmB(stream, 128, QLb, 64, 16384,0,1, KLb, 64, 16384,0,1, A2, 256, 65536,0,1,0,
          256, 256, 64, 32, nullptr, 1.f, 0);
    softmax256_split<<<B_*NH*NLM, 256, 0, stream>>>(A2, (__hip_bfloat16*)a2P, 2097152);
    // pinv (Newton-Schulz, 6 iters)
    init_sc<<<1, 1, 0, stream>>>(SC);
    colsum_max<<<B_*NH, 256, 0, stream>>>(A2, SC);
    rowsum_max<<<B_*NH, 256, 0, stream>>>(A2, SC);
    zinit_split<<<dim3(256, 32), 256, 0, stream>>>(A2, (__hip_bfloat16*)zc_N,
          (__hip_bfloat16*)zc_T, 2097152, SC);
    ushort *cN = zc_N, *cT = zc_T, *nN = zn_N, *nT = zn_T;
    for (int it = 0; it < 6; it++){
      gemmS(stream, a2P, cT, azP, w1T, 1.f, 7.f, -1.f);
      gemmS(stream, azP, w1T, nullptr, w2T, 1.f, 15.f, -1.f);
      gemmS(stream, azP, w2T, nullptr, w1T, 1.f, 13.f, -1.f);
      gemmS(stream, cN, w1T, nN, nT, 0.25f, 0.f, 1.f);
      ushort* s;
      s = cN; cN = nN; nN = s;
      s = cT; cT = nT; nT = s;
    }
    const __hip_bfloat16* Zcb = (const __hip_bfloat16*)cN;
    // V^T per head into BUF (pinv scratch dead except final Z planes at zc_*)
    tr_cvt<<<dim3(64/32, NPAD/32, 32), 256, 0, stream>>>(QKV + 1024, 1, 1536,
          QE, 64, 8, VT, (long long)64*NPAD, NPAD, 64);
    // fused sim3 (flash-style, max-free, 4-way key split) + merge
    sim3_fused<<<dim3(4, 32, 4), 256, 0, stream>>>(QKV, QL2b, VT, AVp, MLp);
    av_merge<<<2048, 256, 0, stream>>>(AVp, MLp, AV);
    // AV^T, ZV = Zc@AV (bf16 out), ZV^T
    tr_cvt<<<dim3(64/32, 256/32, 32), 256, 0, stream>>>(AV, 0, 64, 16384,0,1,
          AVT, 16384, 256, 64);
    gemmB(stream, 64, Zcb, 256, 65536,0,1, AVT, 256, 16384,0,1,
          Zvb, 64, 16384,0,1,1, 256, 64, 256, 32, nullptr, 1.f, 0);
    tr_cvt<<<dim3(64/32, 256/32, 32), 256, 0, stream>>>(Zvb, 1, 64, 16384,0,1,
          ZVT, 16384, 256, 64);
    // fused sim1: OUT1 f32 into BUF
    sim1_fused<<<dim3(NPAD/64, 32), 256, 0, stream>>>(QKV, KL2b, ZVT, BUF);
    // + depthwise conv residual (LDS-staged) -> bf16, projection, residual add
    dwconv_cvt2<<<dim3(NPAD/16, B_), 256, 0, stream>>>(QKV, resw, BUF, OUT1b);
    gemmB(stream, 128, OUT1b, 512, 0,0,1, WoutT, 512, 0,0,1, PROJ, 512, 0,0,1,0,
          B_*NPAD, 512, 512, 1, nullptr, 1.f, 0);
    resid_add<<<dim3(NTOK, B_), 512, 0, stream>>>(H, PROJ, outb);
  };

  // ---- layer 1
  attn_layer(l1_ng, l1_nb, l1_qkv, l1_ow, l1_ob, l1_rw);

  // ---- PPEG (16x16 tiles: ct W=13 -> 1 tile; pth W=78 -> 5x5 tiles)
  ppeg_tiled<<<dim3(1, 16, B_), 512, 0, stream>>>(H, BUF, tc7, tc5, tc3, ct_b7, ct_b5, ct_b3, 11, 13, 1);
  ppeg_copy<<<dim3(169, B_), 512, 0, stream>>>(H, BUF, 11, 13);
  ppeg_tiled<<<dim3(25, 16, B_), 512, 0, stream>>>(H, BUF, tp7, tp5, tp3, pt_b7, pt_b5, pt_b3, 180, 78, 5);
  ppeg_copy<<<dim3(6084, B_), 512, 0, stream>>>(H, BUF, 180, 78);

  // ---- layer 2
  attn_layer(l2_ng, l2_nb, l2_qkv, l2_ow, l2_ob, l2_rw);

  // ---- final LN on cls token
  final_ln<<<B_, 256, 0, stream>>>(H, nrm_g, nrm_b, out);
}

// Round 12
// 2139.208 us; speedup vs baseline: 1.0423x; 1.0423x over previous
//
#include <hip/hip_runtime.h>
#include <hip/hip_bf16.h>
#include <cstdint>

#define B_   4
#define NTOK 6264
#define NPAD 6400
#define D_   512
#define NH   8
#define NLM  256
#define N0   6170
#define PADF (NPAD - NTOK)   // 136
#define MFC1 24704           // B_*N0 padded to x128
#define QE   ((long long)NPAD * 1536)

typedef __attribute__((ext_vector_type(8))) short short8_t;
typedef __attribute__((ext_vector_type(4))) float float4_t;

__device__ __forceinline__ ushort f2b(float x){
  __hip_bfloat16 h = __float2bfloat16(x); return *(ushort*)&h;
}
__device__ __forceinline__ float b2f(ushort u){
  __hip_bfloat16 h = *(__hip_bfloat16*)&u; return __bfloat162float(h);
}
__device__ __forceinline__ float gload(const void* p, int bf, long long i){
  return bf ? __bfloat162float(((const __hip_bfloat16*)p)[i]) : ((const float*)p)[i];
}
__device__ __forceinline__ void atomicMaxF(float* a, float v){
  atomicMax((int*)a, __float_as_int(v));
}
__device__ __forceinline__ void gl_lds16(const void* g, void* l){
  __builtin_amdgcn_global_load_lds(
      (const __attribute__((address_space(1))) void*)g,
      (__attribute__((address_space(3))) void*)l, 16, 0, 0);
}
// single-instruction 2^x (inputs here are tiny: |x| ~ 0.06, no range issues)
__device__ __forceinline__ float fexp2(float x){
#if __has_builtin(__builtin_amdgcn_exp2f)
  return __builtin_amdgcn_exp2f(x);
#else
  return __expf(x * 0.6931471805599453f);
#endif
}

// ===================== fast bf16 NT GEMM (m97-style) ======================
struct GB {
  const __hip_bfloat16* A; const __hip_bfloat16* Bm; void* C; const float* bias;
  int M, N, K, lda, ldb, ldc;
  long long aSO, aSI; int aIn;
  long long bSO, bSI; int bIn;
  long long cSO, cSI; int cIn;
  float beta; int cbf, relu, ksp, klen;
};

template<int BN>
__global__ __launch_bounds__(256) void gemm_bt(GB p){
  __shared__ __align__(16) __hip_bfloat16 As[128*64];
  __shared__ __align__(16) __hip_bfloat16 Bs[BN*64];
  int zz = blockIdx.z;
  int z = zz / p.ksp, ks = zz - z*p.ksp;
  int k0 = ks * p.klen;
  int kend = k0 + p.klen; if (kend > p.K) kend = p.K;
  const __hip_bfloat16* A  = p.A  + (long long)(z/p.aIn)*p.aSO + (long long)(z%p.aIn)*p.aSI;
  const __hip_bfloat16* Bm = p.Bm + (long long)(z/p.bIn)*p.bSO + (long long)(z%p.bIn)*p.bSI;
  long long cOff = (long long)(z/p.cIn)*p.cSO + (long long)(z%p.cIn)*p.cSI;
  int rowBase = blockIdx.y*128, colBase = blockIdx.x*BN;
  int t = threadIdx.x, lane = t & 63;
  int wv = __builtin_amdgcn_readfirstlane(t >> 6);
  int lm = lane & 15, lq = lane >> 4;
  int dr = lane >> 3, dc = lane & 7;
  constexpr int NF = (BN == 128) ? 4 : 2;
  int wm = (wv >> 1) * 64;
  int wn = (BN == 128) ? (wv & 1) * 64 : (wv & 1) * 32;
  float4_t acc[4][NF];
  #pragma unroll
  for (int mi = 0; mi < 4; mi++)
    #pragma unroll
    for (int nf = 0; nf < NF; nf++) acc[mi][nf] = (float4_t)0.f;

  for (int kb = k0; kb < kend; kb += 64){
    #pragma unroll
    for (int d = 0; d < 4; d++){
      int rg = wv*4 + d;
      int row = rg*8 + dr;
      int cc = dc ^ (row & 7);
      gl_lds16(A + (long long)(rowBase + row)*p.lda + kb + cc*8, &As[rg*8*64]);
    }
    #pragma unroll
    for (int d = 0; d < BN/32; d++){
      int rg = wv*(BN/32) + d;
      int row = rg*8 + dr;
      int cc = dc ^ (row & 7);
      gl_lds16(Bm + (long long)(colBase + row)*p.ldb + kb + cc*8, &Bs[rg*8*64]);
    }
    __syncthreads();
    short8_t af[2][4]; short8_t bfv[2][NF];
    #pragma unroll
    for (int ks2 = 0; ks2 < 2; ks2++){
      #pragma unroll
      for (int mi = 0; mi < 4; mi++){
        int r = wm + mi*16 + lm;
        int s = (ks2*4 + lq) ^ (r & 7);
        af[ks2][mi] = *(const short8_t*)&As[r*64 + s*8];
      }
      #pragma unroll
      for (int nf = 0; nf < NF; nf++){
        int r = wn + nf*16 + lm;
        int s = (ks2*4 + lq) ^ (r & 7);
        bfv[ks2][nf] = *(const short8_t*)&Bs[r*64 + s*8];
      }
    }
    #pragma unroll
    for (int ks2 = 0; ks2 < 2; ks2++)
      #pragma unroll
      for (int mi = 0; mi < 4; mi++)
        #pragma unroll
        for (int nf = 0; nf < NF; nf++)
          acc[mi][nf] = __builtin_amdgcn_mfma_f32_16x16x32_bf16(af[ks2][mi], bfv[ks2][nf], acc[mi][nf], 0, 0, 0);
    __syncthreads();
  }
  #pragma unroll
  for (int mi = 0; mi < 4; mi++){
    #pragma unroll
    for (int nf = 0; nf < NF; nf++){
      int c = colBase + wn + nf*16 + lm;
      #pragma unroll
      for (int r = 0; r < 4; r++){
        int m = rowBase + wm + mi*16 + lq*4 + r;
        if (m >= p.M) continue;
        float v = p.beta * acc[mi][nf][r];
        long long ci = cOff + (long long)m*p.ldc + c;
        if (p.ksp > 1){
          atomicAdd((float*)p.C + ci, v);
        } else {
          if (p.bias) v += p.bias[c];
          if (p.relu) v = fmaxf(v, 0.f);
          if (p.cbf) ((__hip_bfloat16*)p.C)[ci] = __float2bfloat16(v);
          else       ((float*)p.C)[ci] = v;
        }
      }
    }
  }
}

// ============== fast split (hi/lo) GEMM for pinv: 64x64 tiles, batch 32 ====
// K=64/stage, 32KB LDS -> 5 blocks/CU. Round-11's K=128 (64KB LDS, 2
// blocks/CU) regressed -74us: occupancy > barrier count for tiny tiles.
struct GS {
  const __hip_bfloat16* A; const __hip_bfloat16* B;
  __hip_bfloat16* outN; __hip_bfloat16* outT;
  long long PS;
  float scale, alphaT, sT;
};

__global__ __launch_bounds__(256) void gemm_bts(GS p){
  __shared__ __align__(16) __hip_bfloat16 Ah[64*64];
  __shared__ __align__(16) __hip_bfloat16 Al[64*64];
  __shared__ __align__(16) __hip_bfloat16 Bh[64*64];
  __shared__ __align__(16) __hip_bfloat16 Bl[64*64];
  int z = blockIdx.z;
  long long zo = (long long)z * 65536;
  const __hip_bfloat16* A = p.A + zo;
  const __hip_bfloat16* B = p.B + zo;
  int rowBase = blockIdx.y*64, colBase = blockIdx.x*64;
  int t = threadIdx.x, lane = t & 63;
  int wv = __builtin_amdgcn_readfirstlane(t >> 6);
  int lm = lane & 15, lq = lane >> 4;
  int dr = lane >> 3, dc = lane & 7;
  int wm = (wv >> 1) * 32, wn = (wv & 1) * 32;
  float4_t acc[2][2];
  #pragma unroll
  for (int mi = 0; mi < 2; mi++){ acc[mi][0] = (float4_t)0.f; acc[mi][1] = (float4_t)0.f; }

  for (int kb = 0; kb < 256; kb += 64){
    #pragma unroll
    for (int d = 0; d < 2; d++){
      int rg = wv*2 + d;
      int row = rg*8 + dr;
      int cc = dc ^ (row & 7);
      gl_lds16(A +        (long long)(rowBase + row)*256 + kb + cc*8, &Ah[rg*8*64]);
      gl_lds16(A + p.PS + (long long)(rowBase + row)*256 + kb + cc*8, &Al[rg*8*64]);
      gl_lds16(B +        (long long)(colBase + row)*256 + kb + cc*8, &Bh[rg*8*64]);
      gl_lds16(B + p.PS + (long long)(colBase + row)*256 + kb + cc*8, &Bl[rg*8*64]);
    }
    __syncthreads();
    #pragma unroll
    for (int ks2 = 0; ks2 < 2; ks2++){
      short8_t ah[2], al2[2], bh[2], bl2[2];
      #pragma unroll
      for (int mi = 0; mi < 2; mi++){
        int r = wm + mi*16 + lm;
        int s = (ks2*4 + lq) ^ (r & 7);
        ah[mi]  = *(const short8_t*)&Ah[r*64 + s*8];
        al2[mi] = *(const short8_t*)&Al[r*64 + s*8];
      }
      #pragma unroll
      for (int nf = 0; nf < 2; nf++){
        int r = wn + nf*16 + lm;
        int s = (ks2*4 + lq) ^ (r & 7);
        bh[nf]  = *(const short8_t*)&Bh[r*64 + s*8];
        bl2[nf] = *(const short8_t*)&Bl[r*64 + s*8];
      }
      #pragma unroll
      for (int mi = 0; mi < 2; mi++)
        #pragma unroll
        for (int nf = 0; nf < 2; nf++){
          acc[mi][nf] = __builtin_amdgcn_mfma_f32_16x16x32_bf16(ah[mi],  bh[nf],  acc[mi][nf], 0, 0, 0);
          acc[mi][nf] = __builtin_amdgcn_mfma_f32_16x16x32_bf16(ah[mi],  bl2[nf], acc[mi][nf], 0, 0, 0);
          acc[mi][nf] = __builtin_amdgcn_mfma_f32_16x16x32_bf16(al2[mi], bh[nf],  acc[mi][nf], 0, 0, 0);
        }
    }
    __syncthreads();
  }
  #pragma unroll
  for (int mi = 0; mi < 2; mi++){
    #pragma unroll
    for (int nf = 0; nf < 2; nf++){
      int c = colBase + wn + nf*16 + lm;
      #pragma unroll
      for (int r = 0; r < 4; r++){
        int m = rowBase + wm + mi*16 + lq*4 + r;
        float v = p.scale * acc[mi][nf][r];
        if (p.outN){
          __hip_bfloat16 hi = __float2bfloat16(v);
          p.outN[zo + (long long)m*256 + c] = hi;
          p.outN[p.PS + zo + (long long)m*256 + c] = __float2bfloat16(v - __bfloat162float(hi));
        }
        if (p.outT){
          float w = p.alphaT * (m == c ? 1.f : 0.f) + p.sT * v;
          __hip_bfloat16 hi = __float2bfloat16(w);
          p.outT[zo + (long long)c*256 + m] = hi;
          p.outT[p.PS + zo + (long long)c*256 + m] = __float2bfloat16(w - __bfloat162float(hi));
        }
      }
    }
  }
}

// ====== fused sim3 (flash-style): S=QL@K^T, max-free softmax, O=P@V^T =====
__global__ __launch_bounds__(256) void sim3_fused(const __hip_bfloat16* QKV,
    const __hip_bfloat16* QL2, const __hip_bfloat16* VT, float* AVp, float* MLp){
  __shared__ __align__(16) __hip_bfloat16 Ks[64*64];
  __shared__ __align__(16) __hip_bfloat16 Ps[4*16*64];
  int z = blockIdx.y, b = z >> 3, h = z & 7;
  int r0 = blockIdx.x * 64;
  int ksp = blockIdx.z;
  int t = threadIdx.x, lane = t & 63;
  int wv = __builtin_amdgcn_readfirstlane(t >> 6);
  int lm = lane & 15, lq = lane >> 4;
  int dr = lane >> 3, dc = lane & 7;
  const __hip_bfloat16* Kb = QKV + (long long)b*QE + h*64 + 512;
  const __hip_bfloat16* Vb = VT + (long long)z*64*NPAD;

  // QL2 A-fragments (constant over key loop)
  short8_t aq[2];
  #pragma unroll
  for (int ks = 0; ks < 2; ks++)
    aq[ks] = *(const short8_t*)(QL2 + (long long)z*NLM*64 + (r0 + wv*16 + lm)*64 + ks*32 + lq*8);

  float l_run[4];
  float4_t oacc[4];
  #pragma unroll
  for (int r = 0; r < 4; r++) l_run[r] = 0.f;
  #pragma unroll
  for (int nf = 0; nf < 4; nf++) oacc[nf] = (float4_t)0.f;

  int kbase = ksp * (NPAD/4);
  for (int kt = 0; kt < (NPAD/4)/64; kt++){
    int k0 = kbase + kt*64;
    __syncthreads();
    // stage K-tile 64 keys x 64 d (swizzled), 2 DMA per wave
    #pragma unroll
    for (int d = 0; d < 2; d++){
      int rg = wv*2 + d;
      int row = rg*8 + dr;
      int cc = dc ^ (row & 7);
      gl_lds16(Kb + (long long)(k0 + row)*1536 + cc*8, &Ks[rg*8*64]);
    }
    __syncthreads();
    // S tile: 16 rows x 64 keys
    float4_t sacc[4];
    #pragma unroll
    for (int nf = 0; nf < 4; nf++) sacc[nf] = (float4_t)0.f;
    #pragma unroll
    for (int ks = 0; ks < 2; ks++){
      #pragma unroll
      for (int nf = 0; nf < 4; nf++){
        int r = nf*16 + lm;
        int s = (ks*4 + lq) ^ (r & 7);
        short8_t bb = *(const short8_t*)&Ks[r*64 + s*8];
        sacc[nf] = __builtin_amdgcn_mfma_f32_16x16x32_bf16(aq[ks], bb, sacc[nf], 0, 0, 0);
      }
    }
    // max-free exp; write unnormalized P' to per-wave Ps (same-wave, no barrier)
    #pragma unroll
    for (int reg = 0; reg < 4; reg++){
      int row = lq*4 + reg;
      #pragma unroll
      for (int nf = 0; nf < 4; nf++){
        float e = fexp2(sacc[nf][reg]);
        l_run[reg] += e;
        int col = nf*16 + lm;
        Ps[(wv*16 + row)*64 + (((col>>3) ^ (row&7))*8) + (col&7)] = __float2bfloat16(e);
      }
    }
    // PV: A = Ps rows (queries), B = VT rows (d), k = keys
    #pragma unroll
    for (int ks = 0; ks < 2; ks++){
      int s = (ks*4 + lq) ^ (lm & 7);
      short8_t ap = *(const short8_t*)&Ps[(wv*16 + lm)*64 + s*8];
      #pragma unroll
      for (int nf = 0; nf < 4; nf++){
        short8_t bb = *(const short8_t*)(Vb + (long long)(nf*16 + lm)*NPAD + k0 + ks*32 + lq*8);
        oacc[nf] = __builtin_amdgcn_mfma_f32_16x16x32_bf16(ap, bb, oacc[nf], 0, 0, 0);
      }
    }
  }
  // one-time row-sum reduce across the 16-lane (lm) group
  #pragma unroll
  for (int reg = 0; reg < 4; reg++)
    #pragma unroll
    for (int mm = 1; mm <= 8; mm <<= 1) l_run[reg] += __shfl_xor(l_run[reg], mm);
  // epilogue: unnormalized partials + l
  long long zb = (long long)(ksp*32 + z);
  #pragma unroll
  for (int nf = 0; nf < 4; nf++){
    #pragma unroll
    for (int reg = 0; reg < 4; reg++){
      int row = r0 + wv*16 + lq*4 + reg;
      AVp[zb*16384 + row*64 + nf*16 + lm] = oacc[nf][reg];
    }
  }
  if (lm == 0){
    #pragma unroll
    for (int reg = 0; reg < 4; reg++){
      int row = r0 + wv*16 + lq*4 + reg;
      MLp[zb*256 + row] = l_run[reg];
    }
  }
}

// merge 4 key-split partials -> AV [z][256][64] f32 (plain sums, m=0)
__global__ __launch_bounds__(256) void av_merge(const float* AVp, const float* MLp, float* AV){
  int i = blockIdx.x*256 + threadIdx.x;
  int d = i & 63, row = (i >> 6) & 255, z = i >> 14;
  float osum = 0.f, lsum = 0.f;
  #pragma unroll
  for (int s = 0; s < 4; s++){
    lsum += MLp[(long long)(s*32+z)*256 + row];
    osum += AVp[(long long)(s*32+z)*16384 + row*64 + d];
  }
  AV[(long long)z*16384 + row*64 + d] = osum / lsum;
}

// ============ fused sim1: S=Q@KL2^T (scale folded), exp2, O=P@ZV ==========
// DMA staging (round-6, verified): K tile staged to LDS via global_load_lds
// (compiler cannot sink DMA); same 32KB buffer reused for ZVT sub-tiles.
__global__ __launch_bounds__(256) void sim1_fused(const __hip_bfloat16* QKV,
    const __hip_bfloat16* KL2, const __hip_bfloat16* ZVT, float* OUT1){
  __shared__ __align__(16) __hip_bfloat16 Ps[64*256];
  __shared__ __align__(16) __hip_bfloat16 Sb[256*64];
  int z = blockIdx.y, b = z >> 3, h = z & 7;
  int n0 = blockIdx.x * 64;
  int t = threadIdx.x, lane = t & 63;
  int wv = __builtin_amdgcn_readfirstlane(t >> 6);
  int lm = lane & 15, lq = lane >> 4;
  int dr = lane >> 3, dc = lane & 7;
  const __hip_bfloat16* Qb = QKV + (long long)b*QE + h*64;
  const __hip_bfloat16* Kb = KL2 + (long long)z*NLM*64;
  const __hip_bfloat16* Zb = ZVT + (long long)z*64*256;

  // stage K tile [256 landmarks][64 d] -> Sb (swizzled), 8 DMA per wave
  #pragma unroll
  for (int d = 0; d < 8; d++){
    int rg = wv*8 + d;
    int row = rg*8 + dr;           // row & 7 == dr
    gl_lds16(Kb + (long long)row*64 + (dc ^ dr)*8, &Sb[rg*8*64]);
  }
  int qrow = n0 + wv*16 + lm;
  short8_t aq[2];
  aq[0] = *(const short8_t*)(Qb + (long long)qrow*1536 + lq*8);
  aq[1] = *(const short8_t*)(Qb + (long long)qrow*1536 + 32 + lq*8);
  __syncthreads();                  // drains DMA + Q loads

  float psum[4] = {0.f, 0.f, 0.f, 0.f};
  int rowb = wv*16 + lq*4;
  #pragma unroll
  for (int nf = 0; nf < 16; nf++){
    float4_t s = (float4_t)0.f;
    #pragma unroll
    for (int ks = 0; ks < 2; ks++){
      int r = nf*16 + lm;
      int s2 = (ks*4 + lq) ^ (r & 7);
      short8_t bb = *(const short8_t*)&Sb[r*64 + s2*8];
      s = __builtin_amdgcn_mfma_f32_16x16x32_bf16(aq[ks], bb, s, 0, 0, 0);
    }
    int col = nf*16 + lm;
    #pragma unroll
    for (int reg = 0; reg < 4; reg++){
      float e = fexp2(s[reg]);
      psum[reg] += e;
      int row = rowb + reg;
      Ps[row*256 + (((col>>3) ^ (row&7))*8) + (col & 7)] = __float2bfloat16(e);
    }
  }
  __syncthreads();                  // all waves done reading K from Sb
  // stage Z tile [64 d][256 keys] as 4 sub-tiles [64][64] into Sb (swizzled)
  #pragma unroll
  for (int d = 0; d < 8; d++){
    int rg = wv*8 + d;
    int sb = rg >> 3, rgl = rg & 7;
    int row = rgl*8 + dr;          // row & 7 == dr
    gl_lds16(Zb + (long long)row*256 + sb*64 + (dc ^ dr)*8,
             &Sb[sb*4096 + rgl*8*64]);
  }
  __syncthreads();                  // drains Z DMA

  float4_t oacc[4];
  #pragma unroll
  for (int nf = 0; nf < 4; nf++) oacc[nf] = (float4_t)0.f;
  int prow = wv*16 + lm;
  #pragma unroll
  for (int ks = 0; ks < 8; ks++){
    int chunk = (ks*4 + lq) ^ (lm & 7);
    short8_t a = *(const short8_t*)&Ps[prow*256 + chunk*8];
    int lc = (ks & 1)*4 + lq;
    #pragma unroll
    for (int nf = 0; nf < 4; nf++){
      int r = nf*16 + lm;
      short8_t bb = *(const short8_t*)&Sb[(ks>>1)*4096 + r*64 + (lc ^ (r & 7))*8];
      oacc[nf] = __builtin_amdgcn_mfma_f32_16x16x32_bf16(a, bb, oacc[nf], 0, 0, 0);
    }
  }
  // deferred row-sum reduce + normalization
  #pragma unroll
  for (int reg = 0; reg < 4; reg++){
    #pragma unroll
    for (int m = 1; m <= 8; m <<= 1) psum[reg] += __shfl_xor(psum[reg], m);
    psum[reg] = 1.f / psum[reg];
  }
  #pragma unroll
  for (int nf = 0; nf < 4; nf++){
    #pragma unroll
    for (int reg = 0; reg < 4; reg++){
      int tok = n0 + wv*16 + lq*4 + reg;
      OUT1[((long long)b*NPAD + tok)*D_ + h*64 + nf*16 + lm] = oacc[nf][reg] * psum[reg];
    }
  }
}

// ============================= softmax ====================================
__global__ __launch_bounds__(256) void softmax256_split(float* S, __hip_bfloat16* P, long long PS){
  long long row = blockIdx.x;
  float* p = S + row * 256;
  int t = threadIdx.x;
  float v = p[t];
  __shared__ float red[256];
  red[t] = v; __syncthreads();
  for (int s = 128; s; s >>= 1){ if (t < s) red[t] = fmaxf(red[t], red[t+s]); __syncthreads(); }
  float m = red[0]; __syncthreads();
  float e = __expf(v - m);
  red[t] = e; __syncthreads();
  for (int s = 128; s; s >>= 1){ if (t < s) red[t] += red[t+s]; __syncthreads(); }
  float r = e / red[0];
  p[t] = r;
  __hip_bfloat16 hi = __float2bfloat16(r);
  P[row*256 + t] = hi;
  P[PS + row*256 + t] = __float2bfloat16(r - __bfloat162float(hi));
}

// ============================ LN / misc ===================================
__global__ __launch_bounds__(256) void ln_pad(const float* H, __hip_bfloat16* X,
                                              const float* g, const float* bb){
  int p = blockIdx.x, b = blockIdx.y, t = threadIdx.x;
  __hip_bfloat16* xo = X + ((long long)b * NPAD + p) * D_;
  if (p < PADF){ xo[t] = __float2bfloat16(0.f); xo[t + 256] = __float2bfloat16(0.f); return; }
  const float* hi = H + ((long long)b * NTOK + (p - PADF)) * D_;
  float x0 = hi[t], x1 = hi[t + 256];
  __shared__ float r1[256], r2[256];
  r1[t] = x0 + x1; r2[t] = x0*x0 + x1*x1;
  __syncthreads();
  for (int s = 128; s; s >>= 1){ if (t < s){ r1[t] += r1[t+s]; r2[t] += r2[t+s]; } __syncthreads(); }
  float mu = r1[0] * (1.f / D_);
  float var = r2[0] * (1.f / D_) - mu*mu;
  float rs = rsqrtf(var + 1e-5f);
  xo[t]       = __float2bfloat16((x0 - mu) * rs * g[t]       + bb[t]);
  xo[t + 256] = __float2bfloat16((x1 - mu) * rs * g[t + 256] + bb[t + 256]);
}

__global__ __launch_bounds__(256) void final_ln(const float* H, const float* g,
                                                const float* bb, float* out){
  int b = blockIdx.x, t = threadIdx.x;
  const float* hi = H + (long long)b * NTOK * D_;
  float x0 = hi[t], x1 = hi[t + 256];
  __shared__ float r1[256], r2[256];
  r1[t] = x0 + x1; r2[t] = x0*x0 + x1*x1;
  __syncthreads();
  for (int s = 128; s; s >>= 1){ if (t < s){ r1[t] += r1[t+s]; r2[t] += r2[t+s]; } __syncthreads(); }
  float mu = r1[0] * (1.f / D_);
  float var = r2[0] * (1.f / D_) - mu*mu;
  float rs = rsqrtf(var + 1e-5f);
  out[b*D_ + t]       = (x0 - mu) * rs * g[t]       + bb[t];
  out[b*D_ + t + 256] = (x1 - mu) * rs * g[t + 256] + bb[t + 256];
}

__global__ __launch_bounds__(256) void build_h(const float* h0, const float* cls, float* H){
  int tpos = blockIdx.x, b = blockIdx.y, t = threadIdx.x;
  float* dst = H + ((long long)b * NTOK + tpos) * D_;
  if (tpos == 0){ dst[t] = cls[t]; dst[t + 256] = cls[t + 256]; return; }
  int i = tpos - 1, src;
  if (i < 10)        src = i;
  else if (i < 179){ int j = i - 10;  src = 10  + (j < 160  ? j : j - 160);  }
  else             { int j = i - 179; src = 170 + (j < 6000 ? j : j - 6000); }
  const float* s = h0 + ((long long)b * N0 + src) * D_;
  dst[t] = s[t]; dst[t + 256] = s[t + 256];
}

__global__ __launch_bounds__(256) void cvt_pad_x(const float* x, __hip_bfloat16* Xb){
  int row = blockIdx.x, t = threadIdx.x;
  __hip_bfloat16* o = Xb + (long long)row * 768;
  if (row >= B_*N0){ o[t] = __float2bfloat16(0.f); o[t+256] = __float2bfloat16(0.f); o[t+512] = __float2bfloat16(0.f); return; }
  const float* s = x + (long long)row * 768;
  o[t]     = __float2bfloat16(s[t]);
  o[t+256] = __float2bfloat16(s[t+256]);
  o[t+512] = __float2bfloat16(s[t+512]);
}

__global__ __launch_bounds__(256) void tr_cvt(const void* in, int inbf, int ldin,
    long long iSO, long long iSI, int iIn, __hip_bfloat16* outp, long long oSO,
    int R, int C){
  __shared__ float sm[32][33];
  int z = blockIdx.z;
  long long ib = (long long)(z/iIn)*iSO + (long long)(z%iIn)*iSI;
  int r0 = blockIdx.y*32, c0 = blockIdx.x*32;
  int tx = threadIdx.x & 31, ty = threadIdx.x >> 5;
  for (int rr = ty; rr < 32; rr += 8)
    sm[rr][tx] = gload(in, inbf, ib + (long long)(r0+rr)*ldin + c0 + tx);
  __syncthreads();
  for (int cc = ty; cc < 32; cc += 8)
    outp[z*oSO + (long long)(c0+cc)*R + r0 + tx] = __float2bfloat16(sm[tx][cc]);
}

// QL/KL: original scales (feed a2 GEMM). QL2/KL2: x log2(e) (feed exp2 paths).
__global__ __launch_bounds__(256) void landmarks2(const __hip_bfloat16* QKV,
                                                  __hip_bfloat16* QL, __hip_bfloat16* KL,
                                                  __hip_bfloat16* QL2, __hip_bfloat16* KL2){
  int j = blockIdx.x, b = blockIdx.y, t = threadIdx.x;
  const __hip_bfloat16* base = QKV + ((long long)b * NPAD + j*25) * 1536;
  float q0 = 0.f, q1 = 0.f, k0 = 0.f, k1 = 0.f;
  #pragma unroll 5
  for (int i = 0; i < 25; i++){
    const __hip_bfloat16* row = base + (long long)i*1536;
    q0 += __bfloat162float(row[t]);
    q1 += __bfloat162float(row[t + 256]);
    k0 += __bfloat162float(row[512 + t]);
    k1 += __bfloat162float(row[512 + t + 256]);
  }
  int h0 = t >> 6, d0 = t & 63;
  int h1 = (t + 256) >> 6, d1 = (t + 256) & 63;
  const float C2 = 0.007213475204444817f;  // 0.04 * 0.125 * log2(e)
  long long i0 = ((long long)(b*8 + h0) * NLM + j) * 64 + d0;
  long long i1 = ((long long)(b*8 + h1) * NLM + j) * 64 + d1;
  QL[i0] = __float2bfloat16(q0 * 0.005f);
  QL[i1] = __float2bfloat16(q1 * 0.005f);
  KL[i0] = __float2bfloat16(k0 * 0.04f);
  KL[i1] = __float2bfloat16(k1 * 0.04f);
  QL2[i0] = __float2bfloat16(q0 * C2);
  QL2[i1] = __float2bfloat16(q1 * C2);
  KL2[i0] = __float2bfloat16(k0 * C2);
  KL2[i1] = __float2bfloat16(k1 * C2);
}

__global__ void init_sc(float* sc){ sc[0] = 0.f; sc[1] = 0.f; }

__global__ __launch_bounds__(256) void colsum_max(const float* A2, float* sc){
  int z = blockIdx.x, t = threadIdx.x;
  const float* a = A2 + (long long)z * 65536;
  float s = 0.f;
  for (int i = 0; i < 256; i++) s += fabsf(a[i*256 + t]);
  __shared__ float red[256];
  red[t] = s; __syncthreads();
  for (int st = 128; st; st >>= 1){ if (t < st) red[t] = fmaxf(red[t], red[t+st]); __syncthreads(); }
  if (t == 0) atomicMaxF(sc + 0, red[0]);
}

__global__ __launch_bounds__(256) void rowsum_max(const float* A2, float* sc){
  int z = blockIdx.x, t = threadIdx.x, w = t >> 6, l = t & 63;
  const float* a = A2 + (long long)z * 65536;
  float mx = 0.f;
  for (int i = w*64; i < (w+1)*64; i++){
    float s = fabsf(a[i*256 + l]) + fabsf(a[i*256 + l + 64])
            + fabsf(a[i*256 + l + 128]) + fabsf(a[i*256 + l + 192]);
    for (int m = 32; m; m >>= 1) s += __shfl_xor(s, m);
    mx = fmaxf(mx, s);
  }
  __shared__ float red[4];
  if (l == 0) red[w] = mx;
  __syncthreads();
  if (t == 0) atomicMaxF(sc + 1, fmaxf(fmaxf(red[0], red[1]), fmaxf(red[2], red[3])));
}

__global__ __launch_bounds__(256) void zinit_split(const float* A2,
    __hip_bfloat16* ZN, __hip_bfloat16* ZT, long long PS, const float* sc){
  int j = blockIdx.x, z = blockIdx.y, i = threadIdx.x;
  float inv = 1.f / (sc[0] * sc[1]);
  float v = A2[(long long)z*65536 + i*256 + j] * inv;
  __hip_bfloat16 hi = __float2bfloat16(v);
  __hip_bfloat16 lo = __float2bfloat16(v - __bfloat162float(hi));
  long long zo = (long long)z*65536;
  ZN[zo + j*256 + i] = hi; ZN[PS + zo + j*256 + i] = lo;
  ZT[zo + i*256 + j] = hi; ZT[PS + zo + i*256 + j] = lo;
}

// LDS-staged depthwise conv (round-10, verified): stage 48 V rows once,
// 4 sequential n-steps per thread from LDS. 11x less cache traffic.
__global__ __launch_bounds__(256) void dwconv_cvt2(const __hip_bfloat16* QKV, const float* rw,
                                                   const float* OUT1, __hip_bfloat16* OUT1b){
  __shared__ __align__(16) __hip_bfloat16 Sv[48*512];   // 48 KB
  int t = threadIdx.x, lane = t & 63;
  int wv = __builtin_amdgcn_readfirstlane(t >> 6);
  int n0 = blockIdx.x * 16;
  int b = blockIdx.y;
  const __hip_bfloat16* Vb = QKV + (long long)b * NPAD * 1536 + 1024;
  // stage rows n0-16 .. n0+31 (one wave stages one 1KB row per DMA)
  for (int r = wv; r < 48; r += 4){
    int nn = n0 - 16 + r;
    if (nn >= 0 && nn < NPAD){
      gl_lds16(Vb + (long long)nn*1536 + lane*8, &Sv[r*512]);
    } else {
      short8_t zz = {0,0,0,0,0,0,0,0};
      *(short8_t*)&Sv[r*512 + lane*8] = zz;
    }
  }
  int ch0 = lane * 8;
  int h = lane >> 3;
  float w[33];
  #pragma unroll
  for (int k = 0; k < 33; k++) w[k] = rw[h*33 + k];
  __syncthreads();
  #pragma unroll 1
  for (int step = 0; step < 4; step++){
    int nl = wv + step*4;            // local token 0..15
    int n = n0 + nl;
    float acc[8] = {};
    #pragma unroll
    for (int k = 0; k < 33; k++){
      short8_t v8 = *(const short8_t*)&Sv[(nl + k)*512 + ch0];
      #pragma unroll
      for (int j = 0; j < 8; j++) acc[j] += w[k] * b2f((ushort)v8[j]);
    }
    long long idx = ((long long)b * NPAD + n) * D_ + ch0;
    float4 o0 = *(const float4*)(OUT1 + idx);
    float4 o1 = *(const float4*)(OUT1 + idx + 4);
    short8_t o;
    o[0] = (short)f2b(o0.x + acc[0]); o[1] = (short)f2b(o0.y + acc[1]);
    o[2] = (short)f2b(o0.z + acc[2]); o[3] = (short)f2b(o0.w + acc[3]);
    o[4] = (short)f2b(o1.x + acc[4]); o[5] = (short)f2b(o1.y + acc[5]);
    o[6] = (short)f2b(o1.z + acc[6]); o[7] = (short)f2b(o1.w + acc[7]);
    *(short8_t*)((ushort*)OUT1b + idx) = o;
  }
}

__global__ __launch_bounds__(512) void resid_add(float* H, const float* O2, const float* ob){
  int i = blockIdx.x, b = blockIdx.y, t = threadIdx.x;
  H[((long long)b * NTOK + i) * D_ + t] +=
      O2[((long long)b * NPAD + i + PADF) * D_ + t] + ob[t];
}

// ------------------- PPEG: LDS weights + float4 staging -------------------
__global__ __launch_bounds__(256) void transpose_w(const float* w, float* wt, int KK){
  int i = blockIdx.x*256 + threadIdx.x;
  if (i < 512*KK){ int ch = i / KK, k = i - ch*KK; wt[(long long)k*512 + ch] = w[i]; }
}

// 16x16 spatial tile x 32 ch, 512 threads (thread = 1 ch, 1 y-row).
// Two sequential 8-wide halves (#pragma unroll 1): live state acc[8]+v[14],
// 96 VGPR, no spill (proven 82us). pk_fma attempted twice (r7/r8); both
// spilled at an observed 128-VGPR cap -> keep scalar form.
__global__ __launch_bounds__(512, 2) void ppeg_tiled(const float* H, float* P,
    const float* t7, const float* t5, const float* t3,
    const float* b7, const float* b5, const float* b3,
    int base, int W, int tilesX){
  __shared__ float smem[484*32];   // 22x22 patch x 32 ch = 61.9 KB
  __shared__ float wsm[83*32 + 32];// 10.6 KB weights + bias-sum
  int ty0 = (blockIdx.x / tilesX) * 16, tx0 = (blockIdx.x % tilesX) * 16;
  int c0 = blockIdx.y * 32, b = blockIdx.z;
  int t = threadIdx.x, ch = t & 31, y = t >> 5;
  int cc = c0 + ch;
  // cooperative weight load (per block)
  for (int i = t; i < 83*32; i += 512){
    int k = i >> 5, c = c0 + (i & 31);
    float w;
    if (k < 49)      w = t7[k*512 + c];
    else if (k < 74) w = t5[(k-49)*512 + c];
    else             w = t3[(k-74)*512 + c];
    wsm[i] = w;
  }
  if (t < 32) wsm[83*32 + t] = b7[c0+t] + b5[c0+t] + b3[c0+t];
  // patch staging (float4 per thread-iter): 484 pos x 8 float4 = 3872 loads
  {
    const float* Hb = H + ((long long)b * NTOK + base) * D_ + c0;
    for (int q = t; q < 3872; q += 512){
      int pos = q >> 3, c4 = (q & 7) * 4;
      int py = pos / 22, px = pos - py*22;
      int yy = ty0 + py - 3, xx = tx0 + px - 3;
      float4 v = make_float4(0.f, 0.f, 0.f, 0.f);
      if (yy >= 0 && yy < W && xx >= 0 && xx < W)
        v = *(const float4*)(Hb + (long long)(yy*W + xx)*D_ + c4);
      *(float4*)&smem[pos*32 + c4] = v;
    }
  }
  __syncthreads();
  int gy = ty0 + y;
  float bsum = wsm[83*32 + ch];
  #pragma unroll 1
  for (int xh = 0; xh < 2; xh++){
    int xb = xh * 8;
    float acc[8];
    #pragma unroll
    for (int x = 0; x < 8; x++) acc[x] = bsum;
    #pragma unroll
    for (int r = 0; r < 7; r++){
      float v[14];
      #pragma unroll
      for (int xx = 0; xx < 14; xx++) v[xx] = smem[((y + r)*22 + xb + xx)*32 + ch];
      #pragma unroll
      for (int kx = 0; kx < 7; kx++){
        float w = wsm[(r*7 + kx)*32 + ch];
        #pragma unroll
        for (int x = 0; x < 8; x++) acc[x] += w * v[x + kx];
      }
      if (r >= 1 && r <= 5){
        #pragma unroll
        for (int kx = 0; kx < 5; kx++){
          float w = wsm[(49 + (r-1)*5 + kx)*32 + ch];
          #pragma unroll
          for (int x = 0; x < 8; x++) acc[x] += w * v[x + kx + 1];
        }
      }
      if (r >= 2 && r <= 4){
        #pragma unroll
        for (int kx = 0; kx < 3; kx++){
          float w = wsm[(74 + (r-2)*3 + kx)*32 + ch];
          #pragma unroll
          for (int x = 0; x < 8; x++) acc[x] += w * v[x + kx + 2];
        }
      }
      if (r == 3){
        #pragma unroll
        for (int x = 0; x < 8; x++) acc[x] += v[x + 3];
      }
    }
    if (gy < W){
      #pragma unroll
      for (int x = 0; x < 8; x++){
        int gx = tx0 + xb + x;
        if (gx < W)
          P[((long long)b * W * W + gy*W + gx) * D_ + cc] = acc[x];
      }
    }
  }
}

__global__ __launch_bounds__(512) void ppeg_copy(float* H, const float* P, int base, int W){
  int pos = blockIdx.x, b = blockIdx.y, t = threadIdx.x;
  H[((long long)b * NTOK + base + pos) * D_ + t] = P[((long long)b * W * W + pos) * D_ + t];
}

// ============================== host side =================================
static void gemmB(hipStream_t st, int BN,
                  const __hip_bfloat16* A, int lda, long long aSO, long long aSI, int aIn,
                  const __hip_bfloat16* Bm, int ldb, long long bSO, long long bSI, int bIn,
                  void* C, int ldc, long long cSO, long long cSI, int cIn, int cbf,
                  int M, int N, int K, int batch,
                  const float* bias, float beta, int relu, int ksp = 1, int klen = 0){
  GB p;
  p.A = A; p.Bm = Bm; p.C = C; p.bias = bias;
  p.M = M; p.N = N; p.K = K; p.lda = lda; p.ldb = ldb; p.ldc = ldc;
  p.aSO = aSO; p.aSI = aSI; p.aIn = aIn;
  p.bSO = bSO; p.bSI = bSI; p.bIn = bIn;
  p.cSO = cSO; p.cSI = cSI; p.cIn = cIn; p.cbf = cbf;
  p.beta = beta; p.relu = relu; p.ksp = ksp; p.klen = (klen > 0) ? klen : K;
  dim3 g(N/BN, (M + 127)/128, batch * ksp), b(256);
  if (BN == 128) gemm_bt<128><<<g, b, 0, st>>>(p);
  else           gemm_bt<64><<<g, b, 0, st>>>(p);
}

static void gemmS(hipStream_t st, const ushort* A, const ushort* B,
                  ushort* oN, ushort* oT, float scale, float alphaT, float sT){
  GS p;
  p.A = (const __hip_bfloat16*)A; p.B = (const __hip_bfloat16*)B;
  p.outN = (__hip_bfloat16*)oN; p.outT = (__hip_bfloat16*)oT;
  p.PS = 2097152; p.scale = scale; p.alphaT = alphaT; p.sT = sT;
  dim3 g(4, 4, 32), b(256);
  gemm_bts<<<g, b, 0, st>>>(p);
}

extern "C" void kernel_launch(void* const* d_in, const int* in_sizes, int n_in,
                              void* d_out, int out_size, void* d_ws, size_t ws_size,
                              hipStream_t stream){
  const float* x      = (const float*)d_in[0];
  const float* fc1_w  = (const float*)d_in[1];
  const float* fc1_b  = (const float*)d_in[2];
  const float* cls    = (const float*)d_in[3];
  const float* l1_ng  = (const float*)d_in[4];
  const float* l1_nb  = (const float*)d_in[5];
  const float* l1_qkv = (const float*)d_in[6];
  const float* l1_ow  = (const float*)d_in[7];
  const float* l1_ob  = (const float*)d_in[8];
  const float* l1_rw  = (const float*)d_in[9];
  const float* ct_w7  = (const float*)d_in[10];
  const float* ct_b7  = (const float*)d_in[11];
  const float* ct_w5  = (const float*)d_in[12];
  const float* ct_b5  = (const float*)d_in[13];
  const float* ct_w3  = (const float*)d_in[14];
  const float* ct_b3  = (const float*)d_in[15];
  const float* pt_w7  = (const float*)d_in[16];
  const float* pt_b7  = (const float*)d_in[17];
  const float* pt_w5  = (const float*)d_in[18];
  const float* pt_b5  = (const float*)d_in[19];
  const float* pt_w3  = (const float*)d_in[20];
  const float* pt_b3  = (const float*)d_in[21];
  const float* l2_ng  = (const float*)d_in[22];
  const float* l2_nb  = (const float*)d_in[23];
  const float* l2_qkv = (const float*)d_in[24];
  const float* l2_ow  = (const float*)d_in[25];
  const float* l2_ob  = (const float*)d_in[26];
  const float* l2_rw  = (const float*)d_in[27];
  const float* nrm_g  = (const float*)d_in[28];
  const float* nrm_b  = (const float*)d_in[29];
  float* out = (float*)d_out;

  // ---- workspace layout (float units); SIMC last ----
  float* ws    = (float*)d_ws;
  float* H     = ws;                      // 12,828,672
  float* BUF   = H + 12828672;            // 13,107,200
  float* QKVr  = BUF + 13107200;          // 19,660,800
  float* QLf   = QKVr + 19660800;         //    262,144
  float* KLf   = QLf + 262144;            //    262,144
  float* AV    = KLf + 262144;            //    524,288
  float* AVTf  = AV + 524288;             //    262,144
  float* ZVf   = AVTf + 262144;           //    262,144
  float* ZVTf  = ZVf + 262144;            //    262,144
  float* WQf   = ZVTf + 262144;           //    393,216
  float* WFf   = WQf + 393216;            //    196,608
  float* WOf   = WFf + 196608;            //    131,072
  float* PWT   = WOf + 131072;            //     84,992
  float* SC    = PWT + 84992;             //          8
  float* SIMC  = SC + 8;                  //  rest (pinv planes / AVp / OUT1b)
  float* tc7 = PWT, *tc5 = tc7 + 49*512, *tc3 = tc5 + 25*512;
  float* tp7 = tc3 + 9*512, *tp5 = tp7 + 49*512, *tp3 = tp5 + 25*512;

  // pinv scratch: A2 f32 + hi/lo plane pairs (PS = 2,097,152 bf16 elems)
  float*  A2   = BUF;
  ushort* a2P  = (ushort*)(BUF + 2097152);
  ushort* zn_N = (ushort*)(BUF + 4194304);
  ushort* zn_T = (ushort*)(BUF + 6291456);
  ushort* zc_N = (ushort*)(BUF + 8388608);
  ushort* zc_T = (ushort*)(BUF + 10485760);
  ushort* azP  = (ushort*)SIMC;
  ushort* w1T  = (ushort*)SIMC + 4194304;
  ushort* w2T  = (ushort*)SIMC + 8388608;
  float*  AVp  = SIMC;                    // 2,097,152 f32 (post-pinv)
  float*  MLp  = SIMC + 2097152;          //    32,768 f32 (l only)

  __hip_bfloat16* Xb    = (__hip_bfloat16*)QKVr;
  __hip_bfloat16* QKV   = (__hip_bfloat16*)QKVr;
  float*          PROJ  = QKVr;
  __hip_bfloat16* XLNb  = (__hip_bfloat16*)BUF;
  __hip_bfloat16* VT    = (__hip_bfloat16*)BUF;         // [32][64][6400]
  __hip_bfloat16* OUT1b = (__hip_bfloat16*)SIMC;
  __hip_bfloat16* QLb   = (__hip_bfloat16*)QLf;
  __hip_bfloat16* KLb   = (__hip_bfloat16*)KLf;
  // exp2-prescaled copies, in dead windows:
  __hip_bfloat16* QL2b  = (__hip_bfloat16*)AV;
  __hip_bfloat16* KL2b  = (__hip_bfloat16*)WQf;
  __hip_bfloat16* AVT   = (__hip_bfloat16*)AVTf;
  __hip_bfloat16* Zvb   = (__hip_bfloat16*)ZVf;
  __hip_bfloat16* ZVT   = (__hip_bfloat16*)ZVTf;
  __hip_bfloat16* WqkvT = (__hip_bfloat16*)WQf;
  __hip_bfloat16* Wfc1T = (__hip_bfloat16*)WFf;
  __hip_bfloat16* WoutT = (__hip_bfloat16*)WOf;

  // ---- one-time weight prep
  transpose_w<<<(512*49+255)/256, 256, 0, stream>>>(ct_w7, tc7, 49);
  transpose_w<<<(512*25+255)/256, 256, 0, stream>>>(ct_w5, tc5, 25);
  transpose_w<<<(512* 9+255)/256, 256, 0, stream>>>(ct_w3, tc3,  9);
  transpose_w<<<(512*49+255)/256, 256, 0, stream>>>(pt_w7, tp7, 49);
  transpose_w<<<(512*25+255)/256, 256, 0, stream>>>(pt_w5, tp5, 25);
  transpose_w<<<(512* 9+255)/256, 256, 0, stream>>>(pt_w3, tp3,  9);
  tr_cvt<<<dim3(512/32, 768/32, 1), 256, 0, stream>>>(fc1_w, 0, 512, 0,0,1, Wfc1T, 0, 768, 512);

  // ---- fc1 + relu -> h0 (BUF f32); gather into H
  cvt_pad_x<<<MFC1, 256, 0, stream>>>(x, Xb);
  gemmB(stream, 128, Xb, 768, 0,0,1, Wfc1T, 768, 0,0,1, BUF, 512, 0,0,1,0,
        MFC1, 512, 768, 1, fc1_b, 1.f, 1);
  build_h<<<dim3(NTOK, B_), 256, 0, stream>>>(BUF, cls, H);

  auto attn_layer = [&](const float* ng, const float* nb, const float* qkvw,
                        const float* outw, const float* outb, const float* resw){
    tr_cvt<<<dim3(1536/32, 512/32, 1), 256, 0, stream>>>(qkvw, 0, 1536, 0,0,1, WqkvT, 0, 512, 1536);
    tr_cvt<<<dim3(512/32, 512/32, 1), 256, 0, stream>>>(outw, 0, 512, 0,0,1, WoutT, 0, 512, 512);
    ln_pad<<<dim3(NPAD, B_), 256, 0, stream>>>(H, XLNb, ng, nb);
    gemmB(stream, 128, XLNb, 512, 0,0,1, WqkvT, 512, 0,0,1, QKV, 1536, 0,0,1,1,
          B_*NPAD, 1536, 512, 1, nullptr, 1.f, 0);
    landmarks2<<<dim3(NLM, B_), 256, 0, stream>>>(QKV, QLb, KLb, QL2b, KL2b);
    // a2 = softmax(q_l @ k_l^T): f32 + hi/lo planes
    gemmB(stream, 128, QLb, 64, 16384,0,1, KLb, 64, 16384,0,1, A2, 256, 65536,0,1,0,
          256, 256, 64, 32, nullptr, 1.f, 0);
    softmax256_split<<<B_*NH*NLM, 256, 0, stream>>>(A2, (__hip_bfloat16*)a2P, 2097152);
    // pinv (Newton-Schulz, 6 iters)
    init_sc<<<1, 1, 0, stream>>>(SC);
    colsum_max<<<B_*NH, 256, 0, stream>>>(A2, SC);
    rowsum_max<<<B_*NH, 256, 0, stream>>>(A2, SC);
    zinit_split<<<dim3(256, 32), 256, 0, stream>>>(A2, (__hip_bfloat16*)zc_N,
          (__hip_bfloat16*)zc_T, 2097152, SC);
    ushort *cN = zc_N, *cT = zc_T, *nN = zn_N, *nT = zn_T;
    for (int it = 0; it < 6; it++){
      gemmS(stream, a2P, cT, azP, w1T, 1.f, 7.f, -1.f);
      gemmS(stream, azP, w1T, nullptr, w2T, 1.f, 15.f, -1.f);
      gemmS(stream, azP, w2T, nullptr, w1T, 1.f, 13.f, -1.f);
      gemmS(stream, cN, w1T, nN, nT, 0.25f, 0.f, 1.f);
      ushort* s;
      s = cN; cN = nN; nN = s;
      s = cT; cT = nT; nT = s;
    }
    const __hip_bfloat16* Zcb = (const __hip_bfloat16*)cN;
    // V^T per head into BUF (pinv scratch dead except final Z planes at zc_*)
    tr_cvt<<<dim3(64/32, NPAD/32, 32), 256, 0, stream>>>(QKV + 1024, 1, 1536,
          QE, 64, 8, VT, (long long)64*NPAD, NPAD, 64);
    // fused sim3 (flash-style, max-free, 4-way key split) + merge
    sim3_fused<<<dim3(4, 32, 4), 256, 0, stream>>>(QKV, QL2b, VT, AVp, MLp);
    av_merge<<<2048, 256, 0, stream>>>(AVp, MLp, AV);
    // AV^T, ZV = Zc@AV (bf16 out), ZV^T
    tr_cvt<<<dim3(64/32, 256/32, 32), 256, 0, stream>>>(AV, 0, 64, 16384,0,1,
          AVT, 16384, 256, 64);
    gemmB(stream, 64, Zcb, 256, 65536,0,1, AVT, 256, 16384,0,1,
          Zvb, 64, 16384,0,1,1, 256, 64, 256, 32, nullptr, 1.f, 0);
    tr_cvt<<<dim3(64/32, 256/32, 32), 256, 0, stream>>>(Zvb, 1, 64, 16384,0,1,
          ZVT, 16384, 256, 64);
    // fused sim1: OUT1 f32 into BUF
    sim1_fused<<<dim3(NPAD/64, 32), 256, 0, stream>>>(QKV, KL2b, ZVT, BUF);
    // + depthwise conv residual (LDS-staged) -> bf16, projection, residual add
    dwconv_cvt2<<<dim3(NPAD/16, B_), 256, 0, stream>>>(QKV, resw, BUF, OUT1b);
    gemmB(stream, 128, OUT1b, 512, 0,0,1, WoutT, 512, 0,0,1, PROJ, 512, 0,0,1,0,
          B_*NPAD, 512, 512, 1, nullptr, 1.f, 0);
    resid_add<<<dim3(NTOK, B_), 512, 0, stream>>>(H, PROJ, outb);
  };

  // ---- layer 1
  attn_layer(l1_ng, l1_nb, l1_qkv, l1_ow, l1_ob, l1_rw);

  // ---- PPEG (16x16 tiles: ct W=13 -> 1 tile; pth W=78 -> 5x5 tiles)
  ppeg_tiled<<<dim3(1, 16, B_), 512, 0, stream>>>(H, BUF, tc7, tc5, tc3, ct_b7, ct_b5, ct_b3, 11, 13, 1);
  ppeg_copy<<<dim3(169, B_), 512, 0, stream>>>(H, BUF, 11, 13);
  ppeg_tiled<<<dim3(25, 16, B_), 512, 0, stream>>>(H, BUF, tp7, tp5, tp3, pt_b7, pt_b5, pt_b3, 180, 78, 5);
  ppeg_copy<<<dim3(6084, B_), 512, 0, stream>>>(H, BUF, 180, 78);

  // ---- layer 2
  attn_layer(l2_ng, l2_nb, l2_qkv, l2_ow, l2_ob, l2_rw);

  // ---- final LN on cls token
  final_ln<<<B_, 256, 0, stream>>>(H, nrm_g, nrm_b, out);
}